// Round 16
// baseline (642.438 us; speedup 1.0000x reference)
//
#include <hip/hip_runtime.h>
#include <math.h>

#define H 128
#define NEGS 0.01f

typedef __attribute__((ext_vector_type(8))) short short8;
typedef __attribute__((ext_vector_type(4))) float f32x4;

__device__ __forceinline__ float lrelu(float x){ return x >= 0.f ? x : NEGS*x; }
__device__ __forceinline__ float eluf(float x){ return x > 0.f ? x : expf(x)-1.f; }
__device__ __forceinline__ float sigm(float x){ return 1.f/(1.f+expf(-x)); }
__device__ __forceinline__ float wred(float v){
  #pragma unroll
  for (int off = 32; off > 0; off >>= 1) v += __shfl_xor(v, off, 64);
  return v;
}
__device__ __forceinline__ float wredmax(float v){
  #pragma unroll
  for (int off = 32; off > 0; off >>= 1) v = fmaxf(v, __shfl_xor(v, off, 64));
  return v;
}
__device__ __forceinline__ unsigned fenc(float f){
  unsigned u = __float_as_uint(f);
  return (u & 0x80000000u) ? ~u : (u | 0x80000000u);
}
__device__ __forceinline__ float fdec(unsigned v){
  return __uint_as_float((v & 0x80000000u) ? (v ^ 0x80000000u) : ~v);
}
__device__ __forceinline__ unsigned short f2bf(float f){
  unsigned u = __float_as_uint(f);
  u += 0x7fffu + ((u >> 16) & 1u);
  return (unsigned short)(u >> 16);
}
__device__ __forceinline__ float bf2f(unsigned short h){
  return __uint_as_float(((unsigned)h) << 16);
}

#define SMS 140   // LDS row stride (ushorts): conflict-free epilogue

// one kernel casts all 8 weight matrices into the contiguous bf16 region
__global__ void k_castall(const float* __restrict__ gW1, const float* __restrict__ gW2,
                          const float* __restrict__ atomW, const float* __restrict__ molW,
                          const float* __restrict__ g1ih, const float* __restrict__ g1hh,
                          const float* __restrict__ g2ih, const float* __restrict__ g2hh,
                          unsigned short* __restrict__ dst){
  int idx = blockIdx.x*256 + threadIdx.x;   // total 262144
  const float* src; int ld = 128; int off;
  if      (idx <  16384){ src = gW1;  ld = 129; off = idx; }
  else if (idx <  32768){ src = gW2;  off = idx -  16384; }
  else if (idx <  49152){ src = atomW;off = idx -  32768; }
  else if (idx <  65536){ src = molW; off = idx -  49152; }
  else if (idx < 114688){ src = g1ih; off = idx -  65536; }
  else if (idx < 163840){ src = g1hh; off = idx - 114688; }
  else if (idx < 212992){ src = g2ih; off = idx - 163840; }
  else                  { src = g2hh; off = idx - 212992; }
  int r = off >> 7, c = off & 127;
  dst[idx] = f2bf(src[r*ld + c]);
}

// fused node init + rdot
__global__ void k_node_init_rd(const float* __restrict__ na, const float* __restrict__ wl,
                               const float* __restrict__ bl, const float* __restrict__ attr,
                               unsigned short* __restrict__ x, float* __restrict__ rdot, int n){
  int i = blockIdx.x*4 + (threadIdx.x >> 6);
  int lane = threadIdx.x & 63;
  if (i >= n) return;
  float nav = na[i];
  float v0 = lrelu(nav*wl[2*lane]   + bl[2*lane]);
  float v1 = lrelu(nav*wl[2*lane+1] + bl[2*lane+1]);
  ushort2 o; o.x = f2bf(v0); o.y = f2bf(v1);
  *(ushort2*)&x[(size_t)i*H + 2*lane] = o;
  float d = bf2f(o.x)*attr[2*lane] + bf2f(o.y)*attr[2*lane+1];
  d = wred(d);
  if (lane == 0) rdot[i] = d;
}

// MFMA GEMM, 256 nodes/block, 4 A-frags/wave.
// out[y*ostride + i*ldy + m]; two-pass LDS-transpose epilogue; optional row-dots.
__global__ __launch_bounds__(256)
void k_gemm_mfma(const unsigned short* __restrict__ X, const unsigned short* __restrict__ Wbf,
                 unsigned short* __restrict__ Y, int n, int ldy, size_t ostride,
                 const float* __restrict__ v1, const float* __restrict__ v2,
                 float* __restrict__ o1, float* __restrict__ o2){
  __shared__ unsigned short sm[128*SMS];
  int w = threadIdx.x >> 6;
  int l = threadIdx.x & 63;
  int nb = blockIdx.x*256;
  int mbase = blockIdx.y*128;
  int row = l & 15;
  int kg  = l >> 4;
  f32x4 acc[4][8];
  #pragma unroll
  for (int f = 0; f < 4; ++f)
    #pragma unroll
    for (int c = 0; c < 8; ++c) acc[f][c] = (f32x4){0.f,0.f,0.f,0.f};
  int ai[4]; bool av[4];
  #pragma unroll
  for (int f = 0; f < 4; ++f){
    ai[f] = nb + f*64 + w*16 + row;
    av[f] = (ai[f] < n);
  }
  #pragma unroll
  for (int ks = 0; ks < 4; ++ks){
    int koff = ks*32 + kg*8;
    short8 A[4];
    #pragma unroll
    for (int f = 0; f < 4; ++f)
      A[f] = av[f] ? *(const short8*)&X[(size_t)ai[f]*H + koff] : (short8){0,0,0,0,0,0,0,0};
    #pragma unroll
    for (int c = 0; c < 8; ++c){
      short8 b = *(const short8*)&Wbf[(size_t)(mbase + c*16 + row)*H + koff];
      acc[0][c] = __builtin_amdgcn_mfma_f32_16x16x32_bf16(A[0], b, acc[0][c], 0, 0, 0);
      acc[1][c] = __builtin_amdgcn_mfma_f32_16x16x32_bf16(A[1], b, acc[1][c], 0, 0, 0);
      acc[2][c] = __builtin_amdgcn_mfma_f32_16x16x32_bf16(A[2], b, acc[2][c], 0, 0, 0);
      acc[3][c] = __builtin_amdgcn_mfma_f32_16x16x32_bf16(A[3], b, acc[3][c], 0, 0, 0);
    }
  }
  if (v1){
    #pragma unroll
    for (int f = 0; f < 4; ++f)
      #pragma unroll
      for (int r = 0; r < 4; ++r){
        float p1 = 0.f, p2 = 0.f;
        #pragma unroll
        for (int c = 0; c < 8; ++c){
          p1 += acc[f][c][r]*v1[c*16 + row];
          if (v2) p2 += acc[f][c][r]*v2[c*16 + row];
        }
        #pragma unroll
        for (int off = 1; off < 16; off <<= 1){
          p1 += __shfl_xor(p1, off, 64);
          if (v2) p2 += __shfl_xor(p2, off, 64);
        }
        int i = nb + f*64 + w*16 + kg*4 + r;
        if (row == 0 && i < n){ o1[i] = p1; if (v2) o2[i] = p2; }
      }
  }
  unsigned short* Yb = Y + (size_t)blockIdx.y*ostride;
  int t = threadIdx.x;
  #pragma unroll
  for (int half = 0; half < 2; ++half){
    if (half) __syncthreads();
    #pragma unroll
    for (int ff = 0; ff < 2; ++ff){
      int f = half*2 + ff;
      #pragma unroll
      for (int c = 0; c < 8; ++c)
        #pragma unroll
        for (int r = 0; r < 4; ++r){
          int nl = ff*64 + w*16 + kg*4 + r;
          sm[nl*SMS + c*16 + row] = f2bf(acc[f][c][r]);
        }
    }
    __syncthreads();
    #pragma unroll
    for (int p = 0; p < 16; ++p){
      int nl = p*8 + (t >> 5);
      int c4 = (t & 31)*4;
      int i = nb + half*128 + nl;
      if (i < n) *(ushort4*)&Yb[(size_t)i*ldy + c4] = *(const ushort4*)&sm[nl*SMS + c4];
    }
  }
}

// GRU gate GEMMs: grid.y = 0..5; 256 nodes/block, 4 A-frags/wave.
__global__ __launch_bounds__(256)
void k_gemm_gru(const unsigned short* __restrict__ Xi, const unsigned short* __restrict__ Xh,
                const unsigned short* __restrict__ Wbf, unsigned short* __restrict__ gi,
                unsigned short* __restrict__ gh, int n){
  __shared__ unsigned short sm[128*SMS];
  int w = threadIdx.x >> 6;
  int l = threadIdx.x & 63;
  int nb = blockIdx.x*256;
  int y = blockIdx.y;
  const unsigned short* X = (y < 3) ? Xi : Xh;
  unsigned short* Y = (y < 3) ? gi : gh;
  int mbase = y*128;
  int cbase = (y < 3 ? y : y-3)*128;
  int row = l & 15;
  int kg  = l >> 4;
  f32x4 acc[4][8];
  #pragma unroll
  for (int f = 0; f < 4; ++f)
    #pragma unroll
    for (int c = 0; c < 8; ++c) acc[f][c] = (f32x4){0.f,0.f,0.f,0.f};
  int ai[4]; bool av[4];
  #pragma unroll
  for (int f = 0; f < 4; ++f){
    ai[f] = nb + f*64 + w*16 + row;
    av[f] = (ai[f] < n);
  }
  #pragma unroll
  for (int ks = 0; ks < 4; ++ks){
    int koff = ks*32 + kg*8;
    short8 A[4];
    #pragma unroll
    for (int f = 0; f < 4; ++f)
      A[f] = av[f] ? *(const short8*)&X[(size_t)ai[f]*H + koff] : (short8){0,0,0,0,0,0,0,0};
    #pragma unroll
    for (int c = 0; c < 8; ++c){
      short8 b = *(const short8*)&Wbf[(size_t)(mbase + c*16 + row)*H + koff];
      acc[0][c] = __builtin_amdgcn_mfma_f32_16x16x32_bf16(A[0], b, acc[0][c], 0, 0, 0);
      acc[1][c] = __builtin_amdgcn_mfma_f32_16x16x32_bf16(A[1], b, acc[1][c], 0, 0, 0);
      acc[2][c] = __builtin_amdgcn_mfma_f32_16x16x32_bf16(A[2], b, acc[2][c], 0, 0, 0);
      acc[3][c] = __builtin_amdgcn_mfma_f32_16x16x32_bf16(A[3], b, acc[3][c], 0, 0, 0);
    }
  }
  int t = threadIdx.x;
  #pragma unroll
  for (int half = 0; half < 2; ++half){
    if (half) __syncthreads();
    #pragma unroll
    for (int ff = 0; ff < 2; ++ff){
      int f = half*2 + ff;
      #pragma unroll
      for (int c = 0; c < 8; ++c)
        #pragma unroll
        for (int r = 0; r < 4; ++r){
          int nl = ff*64 + w*16 + kg*4 + r;
          sm[nl*SMS + c*16 + row] = f2bf(acc[f][c][r]);
        }
    }
    __syncthreads();
    #pragma unroll
    for (int p = 0; p < 16; ++p){
      int nl = p*8 + (t >> 5);
      int c4 = (t & 31)*4;
      int i = nb + half*128 + nl;
      if (i < n) *(ushort4*)&Y[(size_t)i*384 + cbase + c4] = *(const ushort4*)&sm[nl*SMS + c4];
    }
  }
}

// GRUCell combine (ushort2-vectorized)
__global__ void k_gru_combine(const unsigned short* __restrict__ gi, const unsigned short* __restrict__ gh,
                              const float* __restrict__ bih, const float* __restrict__ bhh,
                              unsigned short* __restrict__ x, int n){
  int idx = blockIdx.x*blockDim.x + threadIdx.x;  // over n*64
  if (idx >= n*64) return;
  int i = idx >> 6, t = (idx & 63)*2;
  const unsigned short* gir = gi + (size_t)i*384;
  const unsigned short* ghr = gh + (size_t)i*384;
  ushort2 uir = *(const ushort2*)&gir[t];
  ushort2 uiz = *(const ushort2*)&gir[t+128];
  ushort2 uin = *(const ushort2*)&gir[t+256];
  ushort2 uhr = *(const ushort2*)&ghr[t];
  ushort2 uhz = *(const ushort2*)&ghr[t+128];
  ushort2 uhn = *(const ushort2*)&ghr[t+256];
  ushort2 ux  = *(const ushort2*)&x[(size_t)i*H + t];
  float2 b_ir = *(const float2*)&bih[t], b_iz = *(const float2*)&bih[t+128], b_in = *(const float2*)&bih[t+256];
  float2 b_hr = *(const float2*)&bhh[t], b_hz = *(const float2*)&bhh[t+128], b_hn = *(const float2*)&bhh[t+256];
  ushort2 o;
  {
    float r = sigm(bf2f(uir.x)+b_ir.x + bf2f(uhr.x)+b_hr.x);
    float z = sigm(bf2f(uiz.x)+b_iz.x + bf2f(uhz.x)+b_hz.x);
    float nn = tanhf(bf2f(uin.x)+b_in.x + r*(bf2f(uhn.x)+b_hn.x));
    o.x = f2bf(fmaxf((1.f-z)*nn + z*bf2f(ux.x), 0.f));
  }
  {
    float r = sigm(bf2f(uir.y)+b_ir.y + bf2f(uhr.y)+b_hr.y);
    float z = sigm(bf2f(uiz.y)+b_iz.y + bf2f(uhz.y)+b_hz.y);
    float nn = tanhf(bf2f(uin.y)+b_in.y + r*(bf2f(uhn.y)+b_hn.y));
    o.y = f2bf(fmaxf((1.f-z)*nn + z*bf2f(ux.y), 0.f));
  }
  *(ushort2*)&x[(size_t)i*H + t] = o;
}

// ---------------- CSR build (dst-sorted) ----------------
__global__ void k_hist(const int* __restrict__ key, int* __restrict__ deg, int ne){
  int e = blockIdx.x*blockDim.x + threadIdx.x;
  if (e < ne) atomicAdd(&deg[key[e]], 1);
}
__global__ void k_scan1(const int* __restrict__ deg, int* __restrict__ bsum, int n){
  __shared__ int sd[256];
  int i = blockIdx.x*256 + threadIdx.x;
  sd[threadIdx.x] = (i < n) ? deg[i] : 0;
  __syncthreads();
  for (int s = 128; s > 0; s >>= 1){
    if (threadIdx.x < s) sd[threadIdx.x] += sd[threadIdx.x+s];
    __syncthreads();
  }
  if (threadIdx.x == 0) bsum[blockIdx.x] = sd[0];
}
__global__ void k_scan2(int* __restrict__ bsum, int nb){
  __shared__ int sd[256];
  int t = threadIdx.x;
  int v = (t < nb) ? bsum[t] : 0;
  sd[t] = v;
  __syncthreads();
  for (int off = 1; off < 256; off <<= 1){
    int u = (t >= off) ? sd[t-off] : 0;
    __syncthreads();
    sd[t] += u;
    __syncthreads();
  }
  if (t < nb) bsum[t] = sd[t] - v;
}
__global__ void k_scan3(const int* __restrict__ deg, const int* __restrict__ boff,
                        int* __restrict__ rowptr, int* __restrict__ cursor, int n){
  __shared__ int sd[256];
  int t = threadIdx.x;
  int i = blockIdx.x*256 + t;
  int v = (i < n) ? deg[i] : 0;
  sd[t] = v;
  __syncthreads();
  for (int off = 1; off < 256; off <<= 1){
    int u = (t >= off) ? sd[t-off] : 0;
    __syncthreads();
    sd[t] += u;
    __syncthreads();
  }
  int excl = sd[t] - v + boff[blockIdx.x];
  if (i < n){
    rowptr[i] = excl; cursor[i] = excl;
    if (i == n-1) rowptr[n] = excl + v;
  }
}
// fill: ONE 8B scatter per edge: sea[pos] = {src, ea-bits}
__global__ void k_fill_dst(const int* __restrict__ src, const int* __restrict__ dst,
                           const float* __restrict__ ea, int* __restrict__ cursor,
                           int2* __restrict__ sea, int ne){
  int e = blockIdx.x*blockDim.x + threadIdx.x;
  if (e >= ne) return;
  int pos = atomicAdd(&cursor[dst[e]], 1);
  sea[pos] = make_int2(src[e], __float_as_int(ea[e]));
}

// contiguous copy of gate_W1[:,128]
__global__ void k_pack_gate(const float* __restrict__ gateW1, float* __restrict__ w1col){
  int t = threadIdx.x;
  if (t < H) w1col[t] = gateW1[t*129 + 128];
}

// GATEConv edge logits over dst-sorted positions; 8 lanes/edge.
__global__ __launch_bounds__(256)
void k_edge_logit_gate(const unsigned short* __restrict__ xW1, const float* __restrict__ w1col,
                       const float* __restrict__ attl, const int2* __restrict__ sea,
                       float* __restrict__ logit_s, int ne){
  int tid = threadIdx.x;
  int j = blockIdx.x*32 + (tid >> 3);
  int g = tid & 7;
  if (j >= ne) return;
  int2 se = sea[j];
  int s = se.x;
  float eav = __int_as_float(se.y);
  const unsigned short* xr = &xW1[(size_t)s*H + g*16];
  short8 r0 = *(const short8*)xr;
  short8 r1 = *(const short8*)(xr + 8);
  float acc = 0.f;
  #pragma unroll
  for (int kk = 0; kk < 8; ++kk)
    acc += lrelu(bf2f((unsigned short)r0[kk]) + eav*w1col[g*16 + kk]) * attl[g*16 + kk];
  #pragma unroll
  for (int kk = 0; kk < 8; ++kk)
    acc += lrelu(bf2f((unsigned short)r1[kk]) + eav*w1col[g*16 + 8 + kk]) * attl[g*16 + 8 + kk];
  #pragma unroll
  for (int off = 1; off < 8; off <<= 1) acc += __shfl_xor(acc, off, 64);
  if (g == 0) logit_s[j] = acc;
}

// ---------------- per-node softmax + aggregation ----------------
// Half-wave gather: lanes 0-31 handle even edges, 32-63 odd; each lane loads
// ushort4 (4 cols). Broadcast of per-edge weight/src via __shfl (bpermute).
__global__ void k_node_agg(const int* __restrict__ rowptr, const int2* __restrict__ sea,
                           const float* __restrict__ logit_s, const float* __restrict__ rdot,
                           const unsigned short* __restrict__ val, const float* __restrict__ bias,
                           unsigned short* __restrict__ hbuf, int n){
  int i = blockIdx.x*4 + (threadIdx.x >> 6);
  int lane = threadIdx.x & 63;
  int hl = lane >> 5;
  int cl = lane & 31;
  if (i >= n) return;
  int b = rowptr[i], e1 = rowptr[i+1];
  float rd = rdot[i];
  float m = -1e30f;
  for (int j = b+lane; j < e1; j += 64) m = fmaxf(m, lrelu(logit_s[j] + rd));
  m = wredmax(m);
  float s = 0.f;
  float a0=0.f, a1=0.f, a2=0.f, a3=0.f;
  for (int c0 = b; c0 < e1; c0 += 64){
    int cnt = min(64, e1 - c0);
    float wv = 0.f; int snv = 0;
    if (lane < cnt){
      snv = sea[c0 + lane].x;
      wv = expf(lrelu(logit_s[c0 + lane] + rd) - m);
    }
    s += wred(wv);
    int j = 0;
    for (; j+16 <= cnt; j += 16){
      #pragma unroll
      for (int u = 0; u < 8; ++u){
        int jj = j + 2*u + hl;
        float wq = __shfl(wv, jj, 64);
        int sq = __shfl(snv, jj, 64);
        ushort4 v = *(const ushort4*)&val[(size_t)sq*H + 4*cl];
        a0 += bf2f(v.x)*wq; a1 += bf2f(v.y)*wq; a2 += bf2f(v.z)*wq; a3 += bf2f(v.w)*wq;
      }
    }
    for (; j < cnt; j += 2){
      int jj = j + hl;
      int jjc = jj < 63 ? jj : 63;
      float wq = __shfl(wv, jjc, 64);
      int sq = __shfl(snv, jjc, 64);
      if (jj < cnt){
        ushort4 v = *(const ushort4*)&val[(size_t)sq*H + 4*cl];
        a0 += bf2f(v.x)*wq; a1 += bf2f(v.y)*wq; a2 += bf2f(v.z)*wq; a3 += bf2f(v.w)*wq;
      }
    }
  }
  a0 += __shfl_xor(a0, 32, 64);
  a1 += __shfl_xor(a1, 32, 64);
  a2 += __shfl_xor(a2, 32, 64);
  a3 += __shfl_xor(a3, 32, 64);
  float inv = (s > 0.f) ? 1.f/s : 0.f;
  if (hl == 0){
    float4 bb = *(const float4*)&bias[4*cl];
    ushort4 o;
    o.x = f2bf(eluf(bb.x + a0*inv));
    o.y = f2bf(eluf(bb.y + a1*inv));
    o.z = f2bf(eluf(bb.z + a2*inv));
    o.w = f2bf(eluf(bb.w + a3*inv));
    *(ushort4*)&hbuf[(size_t)i*H + 4*cl] = o;
  }
}

// GAT variant: logit = lrelu(ssrc[src]+sdst[i]) inline
__global__ void k_node_agg_gat(const int* __restrict__ rowptr, const int2* __restrict__ sea,
                               const float* __restrict__ ssrc, const float* __restrict__ sdst,
                               const unsigned short* __restrict__ val, const float* __restrict__ bias,
                               unsigned short* __restrict__ hbuf, int n){
  int i = blockIdx.x*4 + (threadIdx.x >> 6);
  int lane = threadIdx.x & 63;
  int hl = lane >> 5;
  int cl = lane & 31;
  if (i >= n) return;
  int b = rowptr[i], e1 = rowptr[i+1];
  float sdi = sdst[i];
  float m = -1e30f;
  for (int j = b+lane; j < e1; j += 64) m = fmaxf(m, lrelu(ssrc[sea[j].x] + sdi));
  m = wredmax(m);
  float s = 0.f;
  float a0=0.f, a1=0.f, a2=0.f, a3=0.f;
  for (int c0 = b; c0 < e1; c0 += 64){
    int cnt = min(64, e1 - c0);
    float wv = 0.f; int snv = 0;
    if (lane < cnt){
      snv = sea[c0 + lane].x;
      wv = expf(lrelu(ssrc[snv] + sdi) - m);
    }
    s += wred(wv);
    int j = 0;
    for (; j+16 <= cnt; j += 16){
      #pragma unroll
      for (int u = 0; u < 8; ++u){
        int jj = j + 2*u + hl;
        float wq = __shfl(wv, jj, 64);
        int sq = __shfl(snv, jj, 64);
        ushort4 v = *(const ushort4*)&val[(size_t)sq*H + 4*cl];
        a0 += bf2f(v.x)*wq; a1 += bf2f(v.y)*wq; a2 += bf2f(v.z)*wq; a3 += bf2f(v.w)*wq;
      }
    }
    for (; j < cnt; j += 2){
      int jj = j + hl;
      int jjc = jj < 63 ? jj : 63;
      float wq = __shfl(wv, jjc, 64);
      int sq = __shfl(snv, jjc, 64);
      if (jj < cnt){
        ushort4 v = *(const ushort4*)&val[(size_t)sq*H + 4*cl];
        a0 += bf2f(v.x)*wq; a1 += bf2f(v.y)*wq; a2 += bf2f(v.z)*wq; a3 += bf2f(v.w)*wq;
      }
    }
  }
  a0 += __shfl_xor(a0, 32, 64);
  a1 += __shfl_xor(a1, 32, 64);
  a2 += __shfl_xor(a2, 32, 64);
  a3 += __shfl_xor(a3, 32, 64);
  float inv = (s > 0.f) ? 1.f/s : 0.f;
  if (hl == 0){
    float4 bb = *(const float4*)&bias[4*cl];
    ushort4 o;
    o.x = f2bf(eluf(bb.x + a0*inv));
    o.y = f2bf(eluf(bb.y + a1*inv));
    o.z = f2bf(eluf(bb.z + a2*inv));
    o.w = f2bf(eluf(bb.w + a3*inv));
    *(ushort4*)&hbuf[(size_t)i*H + 4*cl] = o;
  }
}

// ---------------- molecule readout ----------------
__global__ void k_colsum(const unsigned short* __restrict__ x, float* __restrict__ outraw,
                         int n, int chunk){
  int t = threadIdx.x; // 64
  int start = blockIdx.x*chunk;
  int end = min(start + chunk, n);
  float s0 = 0.f, s1 = 0.f;
  for (int i = start; i < end; ++i){
    ushort2 v = *(const ushort2*)&x[(size_t)i*H + 2*t];
    s0 += bf2f(v.x); s1 += bf2f(v.y);
  }
  if (start < end){ atomicAdd(&outraw[2*t], s0); atomicAdd(&outraw[2*t+1], s1); }
}
__global__ void k_mol_prep(const float* __restrict__ outraw, const float* __restrict__ molW,
                           const float* __restrict__ attdst, float* __restrict__ hidvec,
                           float* __restrict__ cdst){
  __shared__ float hs[128];
  __shared__ float red[128];
  int t = threadIdx.x;
  float hv = fmaxf(outraw[t], 0.f);
  hs[t] = hv; hidvec[t] = hv;
  __syncthreads();
  float o = 0.f;
  for (int k = 0; k < 128; ++k) o += hs[k]*molW[t*128+k];
  red[t] = o * attdst[t];
  __syncthreads();
  for (int s = 64; s > 0; s >>= 1){
    if (t < s) red[t] += red[t+s];
    __syncthreads();
  }
  if (t == 0) cdst[0] = red[0];
}
// wave-reduced max: ONE atomicMax per wave
__global__ void k_mol_logit(float* __restrict__ a, const float* __restrict__ cdst,
                            unsigned* __restrict__ gmax, int n){
  int i = blockIdx.x*blockDim.x + threadIdx.x;
  int lane = threadIdx.x & 63;
  float l = -1e30f;
  if (i < n){
    l = lrelu(a[i] + cdst[0]);
    a[i] = l;
  }
  float mm = wredmax(l);
  if (lane == 0) atomicMax(gmax, fenc(mm));
}
__global__ void k_mol_exp(float* __restrict__ a, const unsigned* __restrict__ gmax,
                          float* __restrict__ gsum, int n){
  int i = blockIdx.x*blockDim.x + threadIdx.x;
  int lane = threadIdx.x & 63;
  float gm = fdec(gmax[0]);
  float ex = 0.f;
  if (i < n){ ex = expf(a[i] - gm); a[i] = ex; }
  float s = wred(ex);
  if (lane == 0) atomicAdd(gsum, s);
}
__global__ void k_mol_acc(const unsigned short* __restrict__ xs, const float* __restrict__ a,
                          float* __restrict__ num, int n, int chunk){
  int t = threadIdx.x; // 64
  int start = blockIdx.x*chunk;
  int end = min(start + chunk, n);
  float s0 = 0.f, s1 = 0.f;
  for (int i = start; i < end; ++i){
    float ai = a[i];
    ushort2 v = *(const ushort2*)&xs[(size_t)i*H + 2*t];
    s0 += bf2f(v.x)*ai; s1 += bf2f(v.y)*ai;
  }
  if (start < end){ atomicAdd(&num[2*t], s0); atomicAdd(&num[2*t+1], s1); }
}
__global__ void k_mol_final(const float* __restrict__ num, const float* __restrict__ gsum,
                            const float* __restrict__ molb, const float* __restrict__ hidvec,
                            const float* __restrict__ Wih, const float* __restrict__ Whh,
                            const float* __restrict__ bih, const float* __restrict__ bhh,
                            float* __restrict__ out){
  __shared__ float hv[128], hd[128];
  int t = threadIdx.x;
  hv[t] = eluf(num[t]/gsum[0] + molb[t]);
  hd[t] = hidvec[t];
  __syncthreads();
  float gr = bih[t], gz = bih[t+128], gn = bih[t+256];
  float hr = bhh[t], hz = bhh[t+128], hn = bhh[t+256];
  for (int k = 0; k < 128; ++k){
    float h = hv[k], d = hd[k];
    gr += h*Wih[t*128+k];       gz += h*Wih[(t+128)*128+k]; gn += h*Wih[(t+256)*128+k];
    hr += d*Whh[t*128+k];       hz += d*Whh[(t+128)*128+k]; hn += d*Whh[(t+256)*128+k];
  }
  float r = sigm(gr+hr), z = sigm(gz+hz);
  float nn = tanhf(gn + r*hn);
  float o = (1.f-z)*nn + z*hd[t];
  out[t] = fmaxf(o, 0.f);
}

extern "C" void kernel_launch(void* const* d_in, const int* in_sizes, int n_in,
                              void* d_out, int out_size, void* d_ws, size_t ws_size,
                              hipStream_t stream){
  const float* node_attr = (const float*)d_in[0];
  const int*   eidx      = (const int*)d_in[1];
  const float* eattr     = (const float*)d_in[2];
  const float* W_lin1    = (const float*)d_in[3];
  const float* b_lin1    = (const float*)d_in[4];
  const float* gate_W1   = (const float*)d_in[5];
  const float* gate_W2   = (const float*)d_in[6];
  const float* gate_att_l= (const float*)d_in[7];
  const float* gate_att_r= (const float*)d_in[8];
  const float* gate_b    = (const float*)d_in[9];
  const float* g1_Wih    = (const float*)d_in[10];
  const float* g1_Whh    = (const float*)d_in[11];
  const float* g1_bih    = (const float*)d_in[12];
  const float* g1_bhh    = (const float*)d_in[13];
  const float* atom_W    = (const float*)d_in[14];
  const float* atom_as   = (const float*)d_in[15];
  const float* atom_ad   = (const float*)d_in[16];
  const float* atom_b    = (const float*)d_in[17];
  const float* g2_Wih    = (const float*)d_in[18];
  const float* g2_Whh    = (const float*)d_in[19];
  const float* g2_bih    = (const float*)d_in[20];
  const float* g2_bhh    = (const float*)d_in[21];
  const float* mol_W     = (const float*)d_in[22];
  const float* mol_as    = (const float*)d_in[23];
  const float* mol_ad    = (const float*)d_in[24];
  const float* mol_b     = (const float*)d_in[25];
  const float* gm_Wih    = (const float*)d_in[26];
  const float* gm_Whh    = (const float*)d_in[27];
  const float* gm_bih    = (const float*)d_in[28];
  const float* gm_bhh    = (const float*)d_in[29];

  const int n  = in_sizes[0];
  const int ne = in_sizes[1] / 2;
  const int* src = eidx;
  const int* dst = eidx + ne;

  // ---- workspace layout ----
  const size_t NH = (size_t)n * H;
  unsigned short* us = (unsigned short*)d_ws;
  unsigned short* x_bf = us;            // [N,H]
  unsigned short* t0   = us + NH;       // [N,H]
  unsigned short* t1   = us + 2*NH;     // [N,H]
  unsigned short* hb   = us + 3*NH;     // [N,H]
  unsigned short* gi   = us + 4*NH;     // [N,384]
  unsigned short* gh   = us + 7*NH;     // [N,384]
  float* fb = (float*)(us + 10*NH);
  float* rdot = fb;                     // [N]
  float* ssrc = rdot + n;               // [N]
  float* sdst = ssrc + n;               // [N]
  float* logit_s = sdst + n;            // [E]
  int* deg    = (int*)(logit_s + ne);   // [N]
  int* cursor = deg + n;                // [N]
  int* rowptr = cursor + n;             // [N+1]
  int* bsum   = rowptr + n + 1;         // [256]
  size_t ioff = (size_t)(bsum + 256 - (int*)d_ws);
  ioff = (ioff + 1) & ~(size_t)1;       // 8B align for int2
  int2* sea  = (int2*)((int*)d_ws + ioff);   // [E]
  float* outraw = (float*)(sea + ne);   // [128]
  float* hidvec = outraw + 128;         // [128]
  float* cdstp  = hidvec + 128;         // [1]
  unsigned* gmax = (unsigned*)(cdstp + 1);
  float* gsum   = (float*)gmax + 1;
  float* numv   = gsum + 1;             // [128]
  float* w1col  = numv + 128 + 1;       // [128]
  unsigned short* wp = (unsigned short*)(w1col + 128);
  unsigned short* gW1bf  = wp;                 // 128*128 (gW2bf contiguous after)
  unsigned short* gW2bf  = gW1bf  + 128*H;
  unsigned short* atomWbf= gW2bf  + 128*H;
  unsigned short* molWbf = atomWbf+ 128*H;
  unsigned short* g1ihbf = molWbf + 128*H;     // 384*128 (hh contiguous after ih)
  unsigned short* g1hhbf = g1ihbf + 384*H;
  unsigned short* g2ihbf = g1hhbf + 384*H;
  unsigned short* g2hhbf = g2ihbf + 384*H;

  const int nb256      = (n + 255)/256;
  const int nwave4     = (n + 3)/4;
  const int e32_blocks = (ne + 31)/32;
  const int ethr       = (ne + 255)/256;
  const int nthr       = (n + 255)/256;
  const int nb         = (n + 255)/256;
  const int chunk      = (n + 255)/256;
  const int gru_blocks = (n*64 + 255)/256;

  // ---- weight casts + node init + CSR build ----
  k_castall<<<1024,256,0,stream>>>(gate_W1, gate_W2, atom_W, mol_W,
                                   g1_Wih, g1_Whh, g2_Wih, g2_Whh, wp);
  k_pack_gate<<<1,128,0,stream>>>(gate_W1, w1col);
  k_node_init_rd<<<nwave4,256,0,stream>>>(node_attr, W_lin1, b_lin1, gate_att_r, x_bf, rdot, n);
  hipMemsetAsync(deg, 0, (size_t)n*4, stream);
  k_hist<<<ethr,256,0,stream>>>(dst, deg, ne);
  k_scan1<<<nb,256,0,stream>>>(deg, bsum, n);
  k_scan2<<<1,256,0,stream>>>(bsum, nb);
  k_scan3<<<nb,256,0,stream>>>(deg, bsum, rowptr, cursor, n);
  k_fill_dst<<<ethr,256,0,stream>>>(src, dst, eattr, cursor, sea, ne);

  // ---- GATEConv ----
  k_gemm_mfma<<<dim3(nb256,2),256,0,stream>>>(x_bf, gW1bf, t0, n, H, NH,
                                              nullptr, nullptr, nullptr, nullptr);
  k_edge_logit_gate<<<e32_blocks,256,0,stream>>>(t0, w1col, gate_att_l, sea, logit_s, ne);
  k_node_agg<<<nwave4,256,0,stream>>>(rowptr, sea, logit_s, rdot, t1, gate_b, hb, n);
  k_gemm_gru<<<dim3(nb256,6),256,0,stream>>>(hb, x_bf, g1ihbf, gi, gh, n);
  k_gru_combine<<<gru_blocks,256,0,stream>>>(gi, gh, g1_bih, g1_bhh, x_bf, n);

  // ---- GATConv ----
  k_gemm_mfma<<<dim3(nb256,1),256,0,stream>>>(x_bf, atomWbf, t0, n, H, 0,
                                              atom_as, atom_ad, ssrc, sdst);  // xt + dots
  k_node_agg_gat<<<nwave4,256,0,stream>>>(rowptr, sea, ssrc, sdst, t0, atom_b, hb, n);
  k_gemm_gru<<<dim3(nb256,6),256,0,stream>>>(hb, x_bf, g2ihbf, gi, gh, n);
  k_gru_combine<<<gru_blocks,256,0,stream>>>(gi, gh, g2_bih, g2_bhh, x_bf, n);

  // ---- molecule readout ----
  hipMemsetAsync(outraw, 0, 128*4, stream);
  hipMemsetAsync(gmax, 0, 4, stream);
  hipMemsetAsync(gsum, 0, 4, stream);
  hipMemsetAsync(numv, 0, 128*4, stream);
  k_colsum<<<256,64,0,stream>>>(x_bf, outraw, n, chunk);
  k_mol_prep<<<1,128,0,stream>>>(outraw, mol_W, mol_ad, hidvec, cdstp);
  k_gemm_mfma<<<dim3(nb256,1),256,0,stream>>>(x_bf, molWbf, t1, n, H, 0,
                                              mol_as, nullptr, rdot, nullptr);  // xs + dot
  k_mol_logit<<<nthr,256,0,stream>>>(rdot, cdstp, gmax, n);
  k_mol_exp<<<nthr,256,0,stream>>>(rdot, gmax, gsum, n);
  k_mol_acc<<<256,64,0,stream>>>(t1, rdot, numv, n, chunk);
  k_mol_final<<<1,128,0,stream>>>(numv, gsum, mol_b, hidvec,
                                  gm_Wih, gm_Whh, gm_bih, gm_bhh, (float*)d_out);
}

// Round 17
// 617.361 us; speedup vs baseline: 1.0406x; 1.0406x over previous
//
#include <hip/hip_runtime.h>
#include <math.h>

#define H 128
#define NEGS 0.01f

typedef __attribute__((ext_vector_type(8))) short short8;
typedef __attribute__((ext_vector_type(4))) float f32x4;

__device__ __forceinline__ float lrelu(float x){ return x >= 0.f ? x : NEGS*x; }
__device__ __forceinline__ float eluf(float x){ return x > 0.f ? x : expf(x)-1.f; }
__device__ __forceinline__ float sigm(float x){ return 1.f/(1.f+expf(-x)); }
__device__ __forceinline__ float wred(float v){
  #pragma unroll
  for (int off = 32; off > 0; off >>= 1) v += __shfl_xor(v, off, 64);
  return v;
}
__device__ __forceinline__ float wredmax(float v){
  #pragma unroll
  for (int off = 32; off > 0; off >>= 1) v = fmaxf(v, __shfl_xor(v, off, 64));
  return v;
}
__device__ __forceinline__ unsigned fenc(float f){
  unsigned u = __float_as_uint(f);
  return (u & 0x80000000u) ? ~u : (u | 0x80000000u);
}
__device__ __forceinline__ float fdec(unsigned v){
  return __uint_as_float((v & 0x80000000u) ? (v ^ 0x80000000u) : ~v);
}
__device__ __forceinline__ unsigned short f2bf(float f){
  unsigned u = __float_as_uint(f);
  u += 0x7fffu + ((u >> 16) & 1u);
  return (unsigned short)(u >> 16);
}
__device__ __forceinline__ float bf2f(unsigned short h){
  return __uint_as_float(((unsigned)h) << 16);
}
__device__ __forceinline__ float rdlane(float v, int l){
  return __int_as_float(__builtin_amdgcn_readlane(__float_as_int(v), l));
}
__device__ __forceinline__ int rdlanei(int v, int l){
  return __builtin_amdgcn_readlane(v, l);
}

#define SMS 140   // LDS row stride (ushorts): conflict-free epilogue

// one kernel casts all 8 weight matrices into the contiguous bf16 region
__global__ void k_castall(const float* __restrict__ gW1, const float* __restrict__ gW2,
                          const float* __restrict__ atomW, const float* __restrict__ molW,
                          const float* __restrict__ g1ih, const float* __restrict__ g1hh,
                          const float* __restrict__ g2ih, const float* __restrict__ g2hh,
                          unsigned short* __restrict__ dst){
  int idx = blockIdx.x*256 + threadIdx.x;   // total 262144
  const float* src; int ld = 128; int off;
  if      (idx <  16384){ src = gW1;  ld = 129; off = idx; }
  else if (idx <  32768){ src = gW2;  off = idx -  16384; }
  else if (idx <  49152){ src = atomW;off = idx -  32768; }
  else if (idx <  65536){ src = molW; off = idx -  49152; }
  else if (idx < 114688){ src = g1ih; off = idx -  65536; }
  else if (idx < 163840){ src = g1hh; off = idx - 114688; }
  else if (idx < 212992){ src = g2ih; off = idx - 163840; }
  else                  { src = g2hh; off = idx - 212992; }
  int r = off >> 7, c = off & 127;
  dst[idx] = f2bf(src[r*ld + c]);
}

// fused node init + rdot
__global__ void k_node_init_rd(const float* __restrict__ na, const float* __restrict__ wl,
                               const float* __restrict__ bl, const float* __restrict__ attr,
                               unsigned short* __restrict__ x, float* __restrict__ rdot, int n){
  int i = blockIdx.x*4 + (threadIdx.x >> 6);
  int lane = threadIdx.x & 63;
  if (i >= n) return;
  float nav = na[i];
  float v0 = lrelu(nav*wl[2*lane]   + bl[2*lane]);
  float v1 = lrelu(nav*wl[2*lane+1] + bl[2*lane+1]);
  ushort2 o; o.x = f2bf(v0); o.y = f2bf(v1);
  *(ushort2*)&x[(size_t)i*H + 2*lane] = o;
  float d = bf2f(o.x)*attr[2*lane] + bf2f(o.y)*attr[2*lane+1];
  d = wred(d);
  if (lane == 0) rdot[i] = d;
}

// MFMA GEMM, 256 nodes/block, 4 A-frags/wave.
// out[y*ostride + i*ldy + m]; two-pass LDS-transpose epilogue; optional row-dots.
__global__ __launch_bounds__(256)
void k_gemm_mfma(const unsigned short* __restrict__ X, const unsigned short* __restrict__ Wbf,
                 unsigned short* __restrict__ Y, int n, int ldy, size_t ostride,
                 const float* __restrict__ v1, const float* __restrict__ v2,
                 float* __restrict__ o1, float* __restrict__ o2){
  __shared__ unsigned short sm[128*SMS];
  int w = threadIdx.x >> 6;
  int l = threadIdx.x & 63;
  int nb = blockIdx.x*256;
  int mbase = blockIdx.y*128;
  int row = l & 15;
  int kg  = l >> 4;
  f32x4 acc[4][8];
  #pragma unroll
  for (int f = 0; f < 4; ++f)
    #pragma unroll
    for (int c = 0; c < 8; ++c) acc[f][c] = (f32x4){0.f,0.f,0.f,0.f};
  int ai[4]; bool av[4];
  #pragma unroll
  for (int f = 0; f < 4; ++f){
    ai[f] = nb + f*64 + w*16 + row;
    av[f] = (ai[f] < n);
  }
  #pragma unroll
  for (int ks = 0; ks < 4; ++ks){
    int koff = ks*32 + kg*8;
    short8 A[4];
    #pragma unroll
    for (int f = 0; f < 4; ++f)
      A[f] = av[f] ? *(const short8*)&X[(size_t)ai[f]*H + koff] : (short8){0,0,0,0,0,0,0,0};
    #pragma unroll
    for (int c = 0; c < 8; ++c){
      short8 b = *(const short8*)&Wbf[(size_t)(mbase + c*16 + row)*H + koff];
      acc[0][c] = __builtin_amdgcn_mfma_f32_16x16x32_bf16(A[0], b, acc[0][c], 0, 0, 0);
      acc[1][c] = __builtin_amdgcn_mfma_f32_16x16x32_bf16(A[1], b, acc[1][c], 0, 0, 0);
      acc[2][c] = __builtin_amdgcn_mfma_f32_16x16x32_bf16(A[2], b, acc[2][c], 0, 0, 0);
      acc[3][c] = __builtin_amdgcn_mfma_f32_16x16x32_bf16(A[3], b, acc[3][c], 0, 0, 0);
    }
  }
  if (v1){
    #pragma unroll
    for (int f = 0; f < 4; ++f)
      #pragma unroll
      for (int r = 0; r < 4; ++r){
        float p1 = 0.f, p2 = 0.f;
        #pragma unroll
        for (int c = 0; c < 8; ++c){
          p1 += acc[f][c][r]*v1[c*16 + row];
          if (v2) p2 += acc[f][c][r]*v2[c*16 + row];
        }
        #pragma unroll
        for (int off = 1; off < 16; off <<= 1){
          p1 += __shfl_xor(p1, off, 64);
          if (v2) p2 += __shfl_xor(p2, off, 64);
        }
        int i = nb + f*64 + w*16 + kg*4 + r;
        if (row == 0 && i < n){ o1[i] = p1; if (v2) o2[i] = p2; }
      }
  }
  unsigned short* Yb = Y + (size_t)blockIdx.y*ostride;
  int t = threadIdx.x;
  #pragma unroll
  for (int half = 0; half < 2; ++half){
    if (half) __syncthreads();
    #pragma unroll
    for (int ff = 0; ff < 2; ++ff){
      int f = half*2 + ff;
      #pragma unroll
      for (int c = 0; c < 8; ++c)
        #pragma unroll
        for (int r = 0; r < 4; ++r){
          int nl = ff*64 + w*16 + kg*4 + r;
          sm[nl*SMS + c*16 + row] = f2bf(acc[f][c][r]);
        }
    }
    __syncthreads();
    #pragma unroll
    for (int p = 0; p < 16; ++p){
      int nl = p*8 + (t >> 5);
      int c4 = (t & 31)*4;
      int i = nb + half*128 + nl;
      if (i < n) *(ushort4*)&Yb[(size_t)i*ldy + c4] = *(const ushort4*)&sm[nl*SMS + c4];
    }
  }
}

// GRU gate GEMMs: grid.y = 0..5; 256 nodes/block, 4 A-frags/wave.
__global__ __launch_bounds__(256)
void k_gemm_gru(const unsigned short* __restrict__ Xi, const unsigned short* __restrict__ Xh,
                const unsigned short* __restrict__ Wbf, unsigned short* __restrict__ gi,
                unsigned short* __restrict__ gh, int n){
  __shared__ unsigned short sm[128*SMS];
  int w = threadIdx.x >> 6;
  int l = threadIdx.x & 63;
  int nb = blockIdx.x*256;
  int y = blockIdx.y;
  const unsigned short* X = (y < 3) ? Xi : Xh;
  unsigned short* Y = (y < 3) ? gi : gh;
  int mbase = y*128;
  int cbase = (y < 3 ? y : y-3)*128;
  int row = l & 15;
  int kg  = l >> 4;
  f32x4 acc[4][8];
  #pragma unroll
  for (int f = 0; f < 4; ++f)
    #pragma unroll
    for (int c = 0; c < 8; ++c) acc[f][c] = (f32x4){0.f,0.f,0.f,0.f};
  int ai[4]; bool av[4];
  #pragma unroll
  for (int f = 0; f < 4; ++f){
    ai[f] = nb + f*64 + w*16 + row;
    av[f] = (ai[f] < n);
  }
  #pragma unroll
  for (int ks = 0; ks < 4; ++ks){
    int koff = ks*32 + kg*8;
    short8 A[4];
    #pragma unroll
    for (int f = 0; f < 4; ++f)
      A[f] = av[f] ? *(const short8*)&X[(size_t)ai[f]*H + koff] : (short8){0,0,0,0,0,0,0,0};
    #pragma unroll
    for (int c = 0; c < 8; ++c){
      short8 b = *(const short8*)&Wbf[(size_t)(mbase + c*16 + row)*H + koff];
      acc[0][c] = __builtin_amdgcn_mfma_f32_16x16x32_bf16(A[0], b, acc[0][c], 0, 0, 0);
      acc[1][c] = __builtin_amdgcn_mfma_f32_16x16x32_bf16(A[1], b, acc[1][c], 0, 0, 0);
      acc[2][c] = __builtin_amdgcn_mfma_f32_16x16x32_bf16(A[2], b, acc[2][c], 0, 0, 0);
      acc[3][c] = __builtin_amdgcn_mfma_f32_16x16x32_bf16(A[3], b, acc[3][c], 0, 0, 0);
    }
  }
  int t = threadIdx.x;
  #pragma unroll
  for (int half = 0; half < 2; ++half){
    if (half) __syncthreads();
    #pragma unroll
    for (int ff = 0; ff < 2; ++ff){
      int f = half*2 + ff;
      #pragma unroll
      for (int c = 0; c < 8; ++c)
        #pragma unroll
        for (int r = 0; r < 4; ++r){
          int nl = ff*64 + w*16 + kg*4 + r;
          sm[nl*SMS + c*16 + row] = f2bf(acc[f][c][r]);
        }
    }
    __syncthreads();
    #pragma unroll
    for (int p = 0; p < 16; ++p){
      int nl = p*8 + (t >> 5);
      int c4 = (t & 31)*4;
      int i = nb + half*128 + nl;
      if (i < n) *(ushort4*)&Y[(size_t)i*384 + cbase + c4] = *(const ushort4*)&sm[nl*SMS + c4];
    }
  }
}

// GRUCell combine (ushort2-vectorized)
__global__ void k_gru_combine(const unsigned short* __restrict__ gi, const unsigned short* __restrict__ gh,
                              const float* __restrict__ bih, const float* __restrict__ bhh,
                              unsigned short* __restrict__ x, int n){
  int idx = blockIdx.x*blockDim.x + threadIdx.x;  // over n*64
  if (idx >= n*64) return;
  int i = idx >> 6, t = (idx & 63)*2;
  const unsigned short* gir = gi + (size_t)i*384;
  const unsigned short* ghr = gh + (size_t)i*384;
  ushort2 uir = *(const ushort2*)&gir[t];
  ushort2 uiz = *(const ushort2*)&gir[t+128];
  ushort2 uin = *(const ushort2*)&gir[t+256];
  ushort2 uhr = *(const ushort2*)&ghr[t];
  ushort2 uhz = *(const ushort2*)&ghr[t+128];
  ushort2 uhn = *(const ushort2*)&ghr[t+256];
  ushort2 ux  = *(const ushort2*)&x[(size_t)i*H + t];
  float2 b_ir = *(const float2*)&bih[t], b_iz = *(const float2*)&bih[t+128], b_in = *(const float2*)&bih[t+256];
  float2 b_hr = *(const float2*)&bhh[t], b_hz = *(const float2*)&bhh[t+128], b_hn = *(const float2*)&bhh[t+256];
  ushort2 o;
  {
    float r = sigm(bf2f(uir.x)+b_ir.x + bf2f(uhr.x)+b_hr.x);
    float z = sigm(bf2f(uiz.x)+b_iz.x + bf2f(uhz.x)+b_hz.x);
    float nn = tanhf(bf2f(uin.x)+b_in.x + r*(bf2f(uhn.x)+b_hn.x));
    o.x = f2bf(fmaxf((1.f-z)*nn + z*bf2f(ux.x), 0.f));
  }
  {
    float r = sigm(bf2f(uir.y)+b_ir.y + bf2f(uhr.y)+b_hr.y);
    float z = sigm(bf2f(uiz.y)+b_iz.y + bf2f(uhz.y)+b_hz.y);
    float nn = tanhf(bf2f(uin.y)+b_in.y + r*(bf2f(uhn.y)+b_hn.y));
    o.y = f2bf(fmaxf((1.f-z)*nn + z*bf2f(ux.y), 0.f));
  }
  *(ushort2*)&x[(size_t)i*H + t] = o;
}

// ---------------- CSR build (dst-sorted) ----------------
__global__ void k_hist(const int* __restrict__ key, int* __restrict__ deg, int ne){
  int e = blockIdx.x*blockDim.x + threadIdx.x;
  if (e < ne) atomicAdd(&deg[key[e]], 1);
}
__global__ void k_scan1(const int* __restrict__ deg, int* __restrict__ bsum, int n){
  __shared__ int sd[256];
  int i = blockIdx.x*256 + threadIdx.x;
  sd[threadIdx.x] = (i < n) ? deg[i] : 0;
  __syncthreads();
  for (int s = 128; s > 0; s >>= 1){
    if (threadIdx.x < s) sd[threadIdx.x] += sd[threadIdx.x+s];
    __syncthreads();
  }
  if (threadIdx.x == 0) bsum[blockIdx.x] = sd[0];
}
__global__ void k_scan2(int* __restrict__ bsum, int nb){
  __shared__ int sd[256];
  int t = threadIdx.x;
  int v = (t < nb) ? bsum[t] : 0;
  sd[t] = v;
  __syncthreads();
  for (int off = 1; off < 256; off <<= 1){
    int u = (t >= off) ? sd[t-off] : 0;
    __syncthreads();
    sd[t] += u;
    __syncthreads();
  }
  if (t < nb) bsum[t] = sd[t] - v;
}
__global__ void k_scan3(const int* __restrict__ deg, const int* __restrict__ boff,
                        int* __restrict__ rowptr, int* __restrict__ cursor, int n){
  __shared__ int sd[256];
  int t = threadIdx.x;
  int i = blockIdx.x*256 + t;
  int v = (i < n) ? deg[i] : 0;
  sd[t] = v;
  __syncthreads();
  for (int off = 1; off < 256; off <<= 1){
    int u = (t >= off) ? sd[t-off] : 0;
    __syncthreads();
    sd[t] += u;
    __syncthreads();
  }
  int excl = sd[t] - v + boff[blockIdx.x];
  if (i < n){
    rowptr[i] = excl; cursor[i] = excl;
    if (i == n-1) rowptr[n] = excl + v;
  }
}
// fill: ONE 8B scatter per edge: sea[pos] = {src, ea-bits}
__global__ void k_fill_dst(const int* __restrict__ src, const int* __restrict__ dst,
                           const float* __restrict__ ea, int* __restrict__ cursor,
                           int2* __restrict__ sea, int ne){
  int e = blockIdx.x*blockDim.x + threadIdx.x;
  if (e >= ne) return;
  int pos = atomicAdd(&cursor[dst[e]], 1);
  sea[pos] = make_int2(src[e], __float_as_int(ea[e]));
}

// contiguous copy of gate_W1[:,128]
__global__ void k_pack_gate(const float* __restrict__ gateW1, float* __restrict__ w1col){
  int t = threadIdx.x;
  if (t < H) w1col[t] = gateW1[t*129 + 128];
}

// GATEConv edge logits over dst-sorted positions; 8 lanes/edge.
__global__ __launch_bounds__(256)
void k_edge_logit_gate(const unsigned short* __restrict__ xW1, const float* __restrict__ w1col,
                       const float* __restrict__ attl, const int2* __restrict__ sea,
                       float* __restrict__ logit_s, int ne){
  int tid = threadIdx.x;
  int j = blockIdx.x*32 + (tid >> 3);
  int g = tid & 7;
  if (j >= ne) return;
  int2 se = sea[j];
  int s = se.x;
  float eav = __int_as_float(se.y);
  const unsigned short* xr = &xW1[(size_t)s*H + g*16];
  short8 r0 = *(const short8*)xr;
  short8 r1 = *(const short8*)(xr + 8);
  float acc = 0.f;
  #pragma unroll
  for (int kk = 0; kk < 8; ++kk)
    acc += lrelu(bf2f((unsigned short)r0[kk]) + eav*w1col[g*16 + kk]) * attl[g*16 + kk];
  #pragma unroll
  for (int kk = 0; kk < 8; ++kk)
    acc += lrelu(bf2f((unsigned short)r1[kk]) + eav*w1col[g*16 + 8 + kk]) * attl[g*16 + 8 + kk];
  #pragma unroll
  for (int off = 1; off < 8; off <<= 1) acc += __shfl_xor(acc, off, 64);
  if (g == 0) logit_s[j] = acc;
}

// ---------------- per-node softmax + aggregation ----------------
// chunk-64 scheme (R14-proven): readlane broadcast, ushort2 gather, 8-deep unroll.
__global__ void k_node_agg(const int* __restrict__ rowptr, const int2* __restrict__ sea,
                           const float* __restrict__ logit_s, const float* __restrict__ rdot,
                           const unsigned short* __restrict__ val, const float* __restrict__ bias,
                           unsigned short* __restrict__ hbuf, int n){
  int i = blockIdx.x*4 + (threadIdx.x >> 6);
  int lane = threadIdx.x & 63;
  if (i >= n) return;
  int b = rowptr[i], e1 = rowptr[i+1];
  float rd = rdot[i];
  float m = -1e30f;
  for (int j = b+lane; j < e1; j += 64) m = fmaxf(m, lrelu(logit_s[j] + rd));
  m = wredmax(m);
  float s = 0.f, ax = 0.f, ay = 0.f;
  for (int c0 = b; c0 < e1; c0 += 64){
    int cnt = min(64, e1 - c0);
    float wv = 0.f; int snv = 0;
    if (lane < cnt){
      snv = sea[c0 + lane].x;
      wv = expf(lrelu(logit_s[c0 + lane] + rd) - m);
    }
    s += wred(wv);
    int j = 0;
    for (; j+8 <= cnt; j += 8){
      #pragma unroll
      for (int u = 0; u < 8; ++u){
        float wq = rdlane(wv, j+u);
        int sq = rdlanei(snv, j+u);
        ushort2 v = *(const ushort2*)&val[(size_t)sq*H + 2*lane];
        ax += bf2f(v.x)*wq; ay += bf2f(v.y)*wq;
      }
    }
    for (; j < cnt; ++j){
      float wq = rdlane(wv, j);
      int sq = rdlanei(snv, j);
      ushort2 v = *(const ushort2*)&val[(size_t)sq*H + 2*lane];
      ax += bf2f(v.x)*wq; ay += bf2f(v.y)*wq;
    }
  }
  float inv = (s > 0.f) ? 1.f/s : 0.f;
  ushort2 o;
  o.x = f2bf(eluf(bias[2*lane]   + ax*inv));
  o.y = f2bf(eluf(bias[2*lane+1] + ay*inv));
  *(ushort2*)&hbuf[(size_t)i*H + 2*lane] = o;
}

// GAT variant: logit = lrelu(ssrc[src]+sdst[i]) inline
__global__ void k_node_agg_gat(const int* __restrict__ rowptr, const int2* __restrict__ sea,
                               const float* __restrict__ ssrc, const float* __restrict__ sdst,
                               const unsigned short* __restrict__ val, const float* __restrict__ bias,
                               unsigned short* __restrict__ hbuf, int n){
  int i = blockIdx.x*4 + (threadIdx.x >> 6);
  int lane = threadIdx.x & 63;
  if (i >= n) return;
  int b = rowptr[i], e1 = rowptr[i+1];
  float sdi = sdst[i];
  float m = -1e30f;
  for (int j = b+lane; j < e1; j += 64) m = fmaxf(m, lrelu(ssrc[sea[j].x] + sdi));
  m = wredmax(m);
  float s = 0.f, ax = 0.f, ay = 0.f;
  for (int c0 = b; c0 < e1; c0 += 64){
    int cnt = min(64, e1 - c0);
    float wv = 0.f; int snv = 0;
    if (lane < cnt){
      snv = sea[c0 + lane].x;
      wv = expf(lrelu(ssrc[snv] + sdi) - m);
    }
    s += wred(wv);
    int j = 0;
    for (; j+8 <= cnt; j += 8){
      #pragma unroll
      for (int u = 0; u < 8; ++u){
        float wq = rdlane(wv, j+u);
        int sq = rdlanei(snv, j+u);
        ushort2 v = *(const ushort2*)&val[(size_t)sq*H + 2*lane];
        ax += bf2f(v.x)*wq; ay += bf2f(v.y)*wq;
      }
    }
    for (; j < cnt; ++j){
      float wq = rdlane(wv, j);
      int sq = rdlanei(snv, j);
      ushort2 v = *(const ushort2*)&val[(size_t)sq*H + 2*lane];
      ax += bf2f(v.x)*wq; ay += bf2f(v.y)*wq;
    }
  }
  float inv = (s > 0.f) ? 1.f/s : 0.f;
  ushort2 o;
  o.x = f2bf(eluf(bias[2*lane]   + ax*inv));
  o.y = f2bf(eluf(bias[2*lane+1] + ay*inv));
  *(ushort2*)&hbuf[(size_t)i*H + 2*lane] = o;
}

// ---------------- molecule readout ----------------
__global__ void k_colsum(const unsigned short* __restrict__ x, float* __restrict__ outraw,
                         int n, int chunk){
  int t = threadIdx.x; // 64
  int start = blockIdx.x*chunk;
  int end = min(start + chunk, n);
  float s0 = 0.f, s1 = 0.f;
  for (int i = start; i < end; ++i){
    ushort2 v = *(const ushort2*)&x[(size_t)i*H + 2*t];
    s0 += bf2f(v.x); s1 += bf2f(v.y);
  }
  if (start < end){ atomicAdd(&outraw[2*t], s0); atomicAdd(&outraw[2*t+1], s1); }
}
__global__ void k_mol_prep(const float* __restrict__ outraw, const float* __restrict__ molW,
                           const float* __restrict__ attdst, float* __restrict__ hidvec,
                           float* __restrict__ cdst){
  __shared__ float hs[128];
  __shared__ float red[128];
  int t = threadIdx.x;
  float hv = fmaxf(outraw[t], 0.f);
  hs[t] = hv; hidvec[t] = hv;
  __syncthreads();
  float o = 0.f;
  for (int k = 0; k < 128; ++k) o += hs[k]*molW[t*128+k];
  red[t] = o * attdst[t];
  __syncthreads();
  for (int s = 64; s > 0; s >>= 1){
    if (t < s) red[t] += red[t+s];
    __syncthreads();
  }
  if (t == 0) cdst[0] = red[0];
}
// wave-reduced max: ONE atomicMax per wave
__global__ void k_mol_logit(float* __restrict__ a, const float* __restrict__ cdst,
                            unsigned* __restrict__ gmax, int n){
  int i = blockIdx.x*blockDim.x + threadIdx.x;
  int lane = threadIdx.x & 63;
  float l = -1e30f;
  if (i < n){
    l = lrelu(a[i] + cdst[0]);
    a[i] = l;
  }
  float mm = wredmax(l);
  if (lane == 0) atomicMax(gmax, fenc(mm));
}
__global__ void k_mol_exp(float* __restrict__ a, const unsigned* __restrict__ gmax,
                          float* __restrict__ gsum, int n){
  int i = blockIdx.x*blockDim.x + threadIdx.x;
  int lane = threadIdx.x & 63;
  float gm = fdec(gmax[0]);
  float ex = 0.f;
  if (i < n){ ex = expf(a[i] - gm); a[i] = ex; }
  float s = wred(ex);
  if (lane == 0) atomicAdd(gsum, s);
}
__global__ void k_mol_acc(const unsigned short* __restrict__ xs, const float* __restrict__ a,
                          float* __restrict__ num, int n, int chunk){
  int t = threadIdx.x; // 64
  int start = blockIdx.x*chunk;
  int end = min(start + chunk, n);
  float s0 = 0.f, s1 = 0.f;
  for (int i = start; i < end; ++i){
    float ai = a[i];
    ushort2 v = *(const ushort2*)&xs[(size_t)i*H + 2*t];
    s0 += bf2f(v.x)*ai; s1 += bf2f(v.y)*ai;
  }
  if (start < end){ atomicAdd(&num[2*t], s0); atomicAdd(&num[2*t+1], s1); }
}
__global__ void k_mol_final(const float* __restrict__ num, const float* __restrict__ gsum,
                            const float* __restrict__ molb, const float* __restrict__ hidvec,
                            const float* __restrict__ Wih, const float* __restrict__ Whh,
                            const float* __restrict__ bih, const float* __restrict__ bhh,
                            float* __restrict__ out){
  __shared__ float hv[128], hd[128];
  int t = threadIdx.x;
  hv[t] = eluf(num[t]/gsum[0] + molb[t]);
  hd[t] = hidvec[t];
  __syncthreads();
  float gr = bih[t], gz = bih[t+128], gn = bih[t+256];
  float hr = bhh[t], hz = bhh[t+128], hn = bhh[t+256];
  for (int k = 0; k < 128; ++k){
    float h = hv[k], d = hd[k];
    gr += h*Wih[t*128+k];       gz += h*Wih[(t+128)*128+k]; gn += h*Wih[(t+256)*128+k];
    hr += d*Whh[t*128+k];       hz += d*Whh[(t+128)*128+k]; hn += d*Whh[(t+256)*128+k];
  }
  float r = sigm(gr+hr), z = sigm(gz+hz);
  float nn = tanhf(gn + r*hn);
  float o = (1.f-z)*nn + z*hd[t];
  out[t] = fmaxf(o, 0.f);
}

extern "C" void kernel_launch(void* const* d_in, const int* in_sizes, int n_in,
                              void* d_out, int out_size, void* d_ws, size_t ws_size,
                              hipStream_t stream){
  const float* node_attr = (const float*)d_in[0];
  const int*   eidx      = (const int*)d_in[1];
  const float* eattr     = (const float*)d_in[2];
  const float* W_lin1    = (const float*)d_in[3];
  const float* b_lin1    = (const float*)d_in[4];
  const float* gate_W1   = (const float*)d_in[5];
  const float* gate_W2   = (const float*)d_in[6];
  const float* gate_att_l= (const float*)d_in[7];
  const float* gate_att_r= (const float*)d_in[8];
  const float* gate_b    = (const float*)d_in[9];
  const float* g1_Wih    = (const float*)d_in[10];
  const float* g1_Whh    = (const float*)d_in[11];
  const float* g1_bih    = (const float*)d_in[12];
  const float* g1_bhh    = (const float*)d_in[13];
  const float* atom_W    = (const float*)d_in[14];
  const float* atom_as   = (const float*)d_in[15];
  const float* atom_ad   = (const float*)d_in[16];
  const float* atom_b    = (const float*)d_in[17];
  const float* g2_Wih    = (const float*)d_in[18];
  const float* g2_Whh    = (const float*)d_in[19];
  const float* g2_bih    = (const float*)d_in[20];
  const float* g2_bhh    = (const float*)d_in[21];
  const float* mol_W     = (const float*)d_in[22];
  const float* mol_as    = (const float*)d_in[23];
  const float* mol_ad    = (const float*)d_in[24];
  const float* mol_b     = (const float*)d_in[25];
  const float* gm_Wih    = (const float*)d_in[26];
  const float* gm_Whh    = (const float*)d_in[27];
  const float* gm_bih    = (const float*)d_in[28];
  const float* gm_bhh    = (const float*)d_in[29];

  const int n  = in_sizes[0];
  const int ne = in_sizes[1] / 2;
  const int* src = eidx;
  const int* dst = eidx + ne;

  // ---- workspace layout ----
  const size_t NH = (size_t)n * H;
  unsigned short* us = (unsigned short*)d_ws;
  unsigned short* x_bf = us;            // [N,H]
  unsigned short* t0   = us + NH;       // [N,H]
  unsigned short* t1   = us + 2*NH;     // [N,H]
  unsigned short* hb   = us + 3*NH;     // [N,H]
  unsigned short* gi   = us + 4*NH;     // [N,384]
  unsigned short* gh   = us + 7*NH;     // [N,384]
  float* fb = (float*)(us + 10*NH);
  float* rdot = fb;                     // [N]
  float* ssrc = rdot + n;               // [N]
  float* sdst = ssrc + n;               // [N]
  float* logit_s = sdst + n;            // [E]
  int* deg    = (int*)(logit_s + ne);   // [N]
  int* cursor = deg + n;                // [N]
  int* rowptr = cursor + n;             // [N+1]
  int* bsum   = rowptr + n + 1;         // [256]
  size_t ioff = (size_t)(bsum + 256 - (int*)d_ws);
  ioff = (ioff + 1) & ~(size_t)1;       // 8B align for int2
  int2* sea  = (int2*)((int*)d_ws + ioff);   // [E]
  float* outraw = (float*)(sea + ne);   // [128]
  float* hidvec = outraw + 128;         // [128]
  float* cdstp  = hidvec + 128;         // [1]
  unsigned* gmax = (unsigned*)(cdstp + 1);
  float* gsum   = (float*)gmax + 1;
  float* numv   = gsum + 1;             // [128]
  float* w1col  = numv + 128 + 1;       // [128]
  unsigned short* wp = (unsigned short*)(w1col + 128);
  unsigned short* gW1bf  = wp;                 // 128*128 (gW2bf contiguous after)
  unsigned short* gW2bf  = gW1bf  + 128*H;
  unsigned short* atomWbf= gW2bf  + 128*H;
  unsigned short* molWbf = atomWbf+ 128*H;
  unsigned short* g1ihbf = molWbf + 128*H;     // 384*128 (hh contiguous after ih)
  unsigned short* g1hhbf = g1ihbf + 384*H;
  unsigned short* g2ihbf = g1hhbf + 384*H;
  unsigned short* g2hhbf = g2ihbf + 384*H;

  const int nb256      = (n + 255)/256;
  const int nwave4     = (n + 3)/4;
  const int e32_blocks = (ne + 31)/32;
  const int ethr       = (ne + 255)/256;
  const int nthr       = (n + 255)/256;
  const int nb         = (n + 255)/256;
  const int chunk      = (n + 255)/256;
  const int gru_blocks = (n*64 + 255)/256;

  // ---- weight casts + node init + CSR build ----
  k_castall<<<1024,256,0,stream>>>(gate_W1, gate_W2, atom_W, mol_W,
                                   g1_Wih, g1_Whh, g2_Wih, g2_Whh, wp);
  k_pack_gate<<<1,128,0,stream>>>(gate_W1, w1col);
  k_node_init_rd<<<nwave4,256,0,stream>>>(node_attr, W_lin1, b_lin1, gate_att_r, x_bf, rdot, n);
  hipMemsetAsync(deg, 0, (size_t)n*4, stream);
  k_hist<<<ethr,256,0,stream>>>(dst, deg, ne);
  k_scan1<<<nb,256,0,stream>>>(deg, bsum, n);
  k_scan2<<<1,256,0,stream>>>(bsum, nb);
  k_scan3<<<nb,256,0,stream>>>(deg, bsum, rowptr, cursor, n);
  k_fill_dst<<<ethr,256,0,stream>>>(src, dst, eattr, cursor, sea, ne);

  // ---- GATEConv ----
  k_gemm_mfma<<<dim3(nb256,2),256,0,stream>>>(x_bf, gW1bf, t0, n, H, NH,
                                              nullptr, nullptr, nullptr, nullptr);
  k_edge_logit_gate<<<e32_blocks,256,0,stream>>>(t0, w1col, gate_att_l, sea, logit_s, ne);
  k_node_agg<<<nwave4,256,0,stream>>>(rowptr, sea, logit_s, rdot, t1, gate_b, hb, n);
  k_gemm_gru<<<dim3(nb256,6),256,0,stream>>>(hb, x_bf, g1ihbf, gi, gh, n);
  k_gru_combine<<<gru_blocks,256,0,stream>>>(gi, gh, g1_bih, g1_bhh, x_bf, n);

  // ---- GATConv ----
  k_gemm_mfma<<<dim3(nb256,1),256,0,stream>>>(x_bf, atomWbf, t0, n, H, 0,
                                              atom_as, atom_ad, ssrc, sdst);  // xt + dots
  k_node_agg_gat<<<nwave4,256,0,stream>>>(rowptr, sea, ssrc, sdst, t0, atom_b, hb, n);
  k_gemm_gru<<<dim3(nb256,6),256,0,stream>>>(hb, x_bf, g2ihbf, gi, gh, n);
  k_gru_combine<<<gru_blocks,256,0,stream>>>(gi, gh, g2_bih, g2_bhh, x_bf, n);

  // ---- molecule readout ----
  hipMemsetAsync(outraw, 0, 128*4, stream);
  hipMemsetAsync(gmax, 0, 4, stream);
  hipMemsetAsync(gsum, 0, 4, stream);
  hipMemsetAsync(numv, 0, 128*4, stream);
  k_colsum<<<256,64,0,stream>>>(x_bf, outraw, n, chunk);
  k_mol_prep<<<1,128,0,stream>>>(outraw, mol_W, mol_ad, hidvec, cdstp);
  k_gemm_mfma<<<dim3(nb256,1),256,0,stream>>>(x_bf, molWbf, t1, n, H, 0,
                                              mol_as, nullptr, rdot, nullptr);  // xs + dot
  k_mol_logit<<<nthr,256,0,stream>>>(rdot, cdstp, gmax, n);
  k_mol_exp<<<nthr,256,0,stream>>>(rdot, gmax, gsum, n);
  k_mol_acc<<<256,64,0,stream>>>(t1, rdot, numv, n, chunk);
  k_mol_final<<<1,128,0,stream>>>(numv, gsum, mol_b, hidvec,
                                  gm_Wih, gm_Whh, gm_bih, gm_bhh, (float*)d_out);
}

// Round 18
// 608.888 us; speedup vs baseline: 1.0551x; 1.0139x over previous
//
#include <hip/hip_runtime.h>
#include <math.h>

#define H 128
#define NEGS 0.01f

typedef __attribute__((ext_vector_type(8))) short short8;
typedef __attribute__((ext_vector_type(4))) float f32x4;

__device__ __forceinline__ float lrelu(float x){ return x >= 0.f ? x : NEGS*x; }
__device__ __forceinline__ float eluf(float x){ return x > 0.f ? x : expf(x)-1.f; }
__device__ __forceinline__ float sigm(float x){ return 1.f/(1.f+expf(-x)); }
__device__ __forceinline__ float wred(float v){
  #pragma unroll
  for (int off = 32; off > 0; off >>= 1) v += __shfl_xor(v, off, 64);
  return v;
}
__device__ __forceinline__ float wredmax(float v){
  #pragma unroll
  for (int off = 32; off > 0; off >>= 1) v = fmaxf(v, __shfl_xor(v, off, 64));
  return v;
}
__device__ __forceinline__ unsigned fenc(float f){
  unsigned u = __float_as_uint(f);
  return (u & 0x80000000u) ? ~u : (u | 0x80000000u);
}
__device__ __forceinline__ float fdec(unsigned v){
  return __uint_as_float((v & 0x80000000u) ? (v ^ 0x80000000u) : ~v);
}
__device__ __forceinline__ unsigned short f2bf(float f){
  unsigned u = __float_as_uint(f);
  u += 0x7fffu + ((u >> 16) & 1u);
  return (unsigned short)(u >> 16);
}
__device__ __forceinline__ float bf2f(unsigned short h){
  return __uint_as_float(((unsigned)h) << 16);
}
__device__ __forceinline__ float rdlane(float v, int l){
  return __int_as_float(__builtin_amdgcn_readlane(__float_as_int(v), l));
}
__device__ __forceinline__ int rdlanei(int v, int l){
  return __builtin_amdgcn_readlane(v, l);
}

#define SMS 140   // LDS row stride (ushorts): conflict-free epilogue

// casts all 8 weight matrices + zeros deg + packs w1col + zeros mol scalars
__global__ void k_castall(const float* __restrict__ gW1, const float* __restrict__ gW2,
                          const float* __restrict__ atomW, const float* __restrict__ molW,
                          const float* __restrict__ g1ih, const float* __restrict__ g1hh,
                          const float* __restrict__ g2ih, const float* __restrict__ g2hh,
                          unsigned short* __restrict__ dst,
                          int* __restrict__ deg, int n, float* __restrict__ w1col,
                          float* __restrict__ outraw, unsigned* __restrict__ gmax,
                          float* __restrict__ gsum, float* __restrict__ numv){
  int idx = blockIdx.x*256 + threadIdx.x;   // total 262144
  // fused side jobs
  if (idx < n) deg[idx] = 0;
  if (idx < 128){
    w1col[idx] = gW1[idx*129 + 128];
    outraw[idx] = 0.f;
    numv[idx] = 0.f;
  }
  if (idx == 0){ gmax[0] = 0u; gsum[0] = 0.f; }
  const float* src; int ld = 128; int off;
  if      (idx <  16384){ src = gW1;  ld = 129; off = idx; }
  else if (idx <  32768){ src = gW2;  off = idx -  16384; }
  else if (idx <  49152){ src = atomW;off = idx -  32768; }
  else if (idx <  65536){ src = molW; off = idx -  49152; }
  else if (idx < 114688){ src = g1ih; off = idx -  65536; }
  else if (idx < 163840){ src = g1hh; off = idx - 114688; }
  else if (idx < 212992){ src = g2ih; off = idx - 163840; }
  else                  { src = g2hh; off = idx - 212992; }
  int r = off >> 7, c = off & 127;
  dst[idx] = f2bf(src[r*ld + c]);
}

// fused node init + rdot
__global__ void k_node_init_rd(const float* __restrict__ na, const float* __restrict__ wl,
                               const float* __restrict__ bl, const float* __restrict__ attr,
                               unsigned short* __restrict__ x, float* __restrict__ rdot, int n){
  int i = blockIdx.x*4 + (threadIdx.x >> 6);
  int lane = threadIdx.x & 63;
  if (i >= n) return;
  float nav = na[i];
  float v0 = lrelu(nav*wl[2*lane]   + bl[2*lane]);
  float v1 = lrelu(nav*wl[2*lane+1] + bl[2*lane+1]);
  ushort2 o; o.x = f2bf(v0); o.y = f2bf(v1);
  *(ushort2*)&x[(size_t)i*H + 2*lane] = o;
  float d = bf2f(o.x)*attr[2*lane] + bf2f(o.y)*attr[2*lane+1];
  d = wred(d);
  if (lane == 0) rdot[i] = d;
}

// MFMA GEMM, 256 nodes/block, 4 A-frags/wave.
__global__ __launch_bounds__(256)
void k_gemm_mfma(const unsigned short* __restrict__ X, const unsigned short* __restrict__ Wbf,
                 unsigned short* __restrict__ Y, int n, int ldy, size_t ostride,
                 const float* __restrict__ v1, const float* __restrict__ v2,
                 float* __restrict__ o1, float* __restrict__ o2){
  __shared__ unsigned short sm[128*SMS];
  int w = threadIdx.x >> 6;
  int l = threadIdx.x & 63;
  int nb = blockIdx.x*256;
  int mbase = blockIdx.y*128;
  int row = l & 15;
  int kg  = l >> 4;
  f32x4 acc[4][8];
  #pragma unroll
  for (int f = 0; f < 4; ++f)
    #pragma unroll
    for (int c = 0; c < 8; ++c) acc[f][c] = (f32x4){0.f,0.f,0.f,0.f};
  int ai[4]; bool av[4];
  #pragma unroll
  for (int f = 0; f < 4; ++f){
    ai[f] = nb + f*64 + w*16 + row;
    av[f] = (ai[f] < n);
  }
  #pragma unroll
  for (int ks = 0; ks < 4; ++ks){
    int koff = ks*32 + kg*8;
    short8 A[4];
    #pragma unroll
    for (int f = 0; f < 4; ++f)
      A[f] = av[f] ? *(const short8*)&X[(size_t)ai[f]*H + koff] : (short8){0,0,0,0,0,0,0,0};
    #pragma unroll
    for (int c = 0; c < 8; ++c){
      short8 b = *(const short8*)&Wbf[(size_t)(mbase + c*16 + row)*H + koff];
      acc[0][c] = __builtin_amdgcn_mfma_f32_16x16x32_bf16(A[0], b, acc[0][c], 0, 0, 0);
      acc[1][c] = __builtin_amdgcn_mfma_f32_16x16x32_bf16(A[1], b, acc[1][c], 0, 0, 0);
      acc[2][c] = __builtin_amdgcn_mfma_f32_16x16x32_bf16(A[2], b, acc[2][c], 0, 0, 0);
      acc[3][c] = __builtin_amdgcn_mfma_f32_16x16x32_bf16(A[3], b, acc[3][c], 0, 0, 0);
    }
  }
  if (v1){
    #pragma unroll
    for (int f = 0; f < 4; ++f)
      #pragma unroll
      for (int r = 0; r < 4; ++r){
        float p1 = 0.f, p2 = 0.f;
        #pragma unroll
        for (int c = 0; c < 8; ++c){
          p1 += acc[f][c][r]*v1[c*16 + row];
          if (v2) p2 += acc[f][c][r]*v2[c*16 + row];
        }
        #pragma unroll
        for (int off = 1; off < 16; off <<= 1){
          p1 += __shfl_xor(p1, off, 64);
          if (v2) p2 += __shfl_xor(p2, off, 64);
        }
        int i = nb + f*64 + w*16 + kg*4 + r;
        if (row == 0 && i < n){ o1[i] = p1; if (v2) o2[i] = p2; }
      }
  }
  unsigned short* Yb = Y + (size_t)blockIdx.y*ostride;
  int t = threadIdx.x;
  #pragma unroll
  for (int half = 0; half < 2; ++half){
    if (half) __syncthreads();
    #pragma unroll
    for (int ff = 0; ff < 2; ++ff){
      int f = half*2 + ff;
      #pragma unroll
      for (int c = 0; c < 8; ++c)
        #pragma unroll
        for (int r = 0; r < 4; ++r){
          int nl = ff*64 + w*16 + kg*4 + r;
          sm[nl*SMS + c*16 + row] = f2bf(acc[f][c][r]);
        }
    }
    __syncthreads();
    #pragma unroll
    for (int p = 0; p < 16; ++p){
      int nl = p*8 + (t >> 5);
      int c4 = (t & 31)*4;
      int i = nb + half*128 + nl;
      if (i < n) *(ushort4*)&Yb[(size_t)i*ldy + c4] = *(const ushort4*)&sm[nl*SMS + c4];
    }
  }
}

// GRU gate GEMMs: grid.y = 0..5; 256 nodes/block, 4 A-frags/wave.
__global__ __launch_bounds__(256)
void k_gemm_gru(const unsigned short* __restrict__ Xi, const unsigned short* __restrict__ Xh,
                const unsigned short* __restrict__ Wbf, unsigned short* __restrict__ gi,
                unsigned short* __restrict__ gh, int n){
  __shared__ unsigned short sm[128*SMS];
  int w = threadIdx.x >> 6;
  int l = threadIdx.x & 63;
  int nb = blockIdx.x*256;
  int y = blockIdx.y;
  const unsigned short* X = (y < 3) ? Xi : Xh;
  unsigned short* Y = (y < 3) ? gi : gh;
  int mbase = y*128;
  int cbase = (y < 3 ? y : y-3)*128;
  int row = l & 15;
  int kg  = l >> 4;
  f32x4 acc[4][8];
  #pragma unroll
  for (int f = 0; f < 4; ++f)
    #pragma unroll
    for (int c = 0; c < 8; ++c) acc[f][c] = (f32x4){0.f,0.f,0.f,0.f};
  int ai[4]; bool av[4];
  #pragma unroll
  for (int f = 0; f < 4; ++f){
    ai[f] = nb + f*64 + w*16 + row;
    av[f] = (ai[f] < n);
  }
  #pragma unroll
  for (int ks = 0; ks < 4; ++ks){
    int koff = ks*32 + kg*8;
    short8 A[4];
    #pragma unroll
    for (int f = 0; f < 4; ++f)
      A[f] = av[f] ? *(const short8*)&X[(size_t)ai[f]*H + koff] : (short8){0,0,0,0,0,0,0,0};
    #pragma unroll
    for (int c = 0; c < 8; ++c){
      short8 b = *(const short8*)&Wbf[(size_t)(mbase + c*16 + row)*H + koff];
      acc[0][c] = __builtin_amdgcn_mfma_f32_16x16x32_bf16(A[0], b, acc[0][c], 0, 0, 0);
      acc[1][c] = __builtin_amdgcn_mfma_f32_16x16x32_bf16(A[1], b, acc[1][c], 0, 0, 0);
      acc[2][c] = __builtin_amdgcn_mfma_f32_16x16x32_bf16(A[2], b, acc[2][c], 0, 0, 0);
      acc[3][c] = __builtin_amdgcn_mfma_f32_16x16x32_bf16(A[3], b, acc[3][c], 0, 0, 0);
    }
  }
  int t = threadIdx.x;
  #pragma unroll
  for (int half = 0; half < 2; ++half){
    if (half) __syncthreads();
    #pragma unroll
    for (int ff = 0; ff < 2; ++ff){
      int f = half*2 + ff;
      #pragma unroll
      for (int c = 0; c < 8; ++c)
        #pragma unroll
        for (int r = 0; r < 4; ++r){
          int nl = ff*64 + w*16 + kg*4 + r;
          sm[nl*SMS + c*16 + row] = f2bf(acc[f][c][r]);
        }
    }
    __syncthreads();
    #pragma unroll
    for (int p = 0; p < 16; ++p){
      int nl = p*8 + (t >> 5);
      int c4 = (t & 31)*4;
      int i = nb + half*128 + nl;
      if (i < n) *(ushort4*)&Y[(size_t)i*384 + cbase + c4] = *(const ushort4*)&sm[nl*SMS + c4];
    }
  }
}

// GRUCell combine (ushort2-vectorized)
__global__ void k_gru_combine(const unsigned short* __restrict__ gi, const unsigned short* __restrict__ gh,
                              const float* __restrict__ bih, const float* __restrict__ bhh,
                              unsigned short* __restrict__ x, int n){
  int idx = blockIdx.x*blockDim.x + threadIdx.x;  // over n*64
  if (idx >= n*64) return;
  int i = idx >> 6, t = (idx & 63)*2;
  const unsigned short* gir = gi + (size_t)i*384;
  const unsigned short* ghr = gh + (size_t)i*384;
  ushort2 uir = *(const ushort2*)&gir[t];
  ushort2 uiz = *(const ushort2*)&gir[t+128];
  ushort2 uin = *(const ushort2*)&gir[t+256];
  ushort2 uhr = *(const ushort2*)&ghr[t];
  ushort2 uhz = *(const ushort2*)&ghr[t+128];
  ushort2 uhn = *(const ushort2*)&ghr[t+256];
  ushort2 ux  = *(const ushort2*)&x[(size_t)i*H + t];
  float2 b_ir = *(const float2*)&bih[t], b_iz = *(const float2*)&bih[t+128], b_in = *(const float2*)&bih[t+256];
  float2 b_hr = *(const float2*)&bhh[t], b_hz = *(const float2*)&bhh[t+128], b_hn = *(const float2*)&bhh[t+256];
  ushort2 o;
  {
    float r = sigm(bf2f(uir.x)+b_ir.x + bf2f(uhr.x)+b_hr.x);
    float z = sigm(bf2f(uiz.x)+b_iz.x + bf2f(uhz.x)+b_hz.x);
    float nn = tanhf(bf2f(uin.x)+b_in.x + r*(bf2f(uhn.x)+b_hn.x));
    o.x = f2bf(fmaxf((1.f-z)*nn + z*bf2f(ux.x), 0.f));
  }
  {
    float r = sigm(bf2f(uir.y)+b_ir.y + bf2f(uhr.y)+b_hr.y);
    float z = sigm(bf2f(uiz.y)+b_iz.y + bf2f(uhz.y)+b_hz.y);
    float nn = tanhf(bf2f(uin.y)+b_in.y + r*(bf2f(uhn.y)+b_hn.y));
    o.y = f2bf(fmaxf((1.f-z)*nn + z*bf2f(ux.y), 0.f));
  }
  *(ushort2*)&x[(size_t)i*H + t] = o;
}

// ---------------- CSR build (dst-sorted) ----------------
__global__ void k_hist(const int* __restrict__ key, int* __restrict__ deg, int ne){
  int e = blockIdx.x*blockDim.x + threadIdx.x;
  if (e < ne) atomicAdd(&deg[key[e]], 1);
}
__global__ void k_scan1(const int* __restrict__ deg, int* __restrict__ bsum, int n){
  __shared__ int sd[256];
  int i = blockIdx.x*256 + threadIdx.x;
  sd[threadIdx.x] = (i < n) ? deg[i] : 0;
  __syncthreads();
  for (int s = 128; s > 0; s >>= 1){
    if (threadIdx.x < s) sd[threadIdx.x] += sd[threadIdx.x+s];
    __syncthreads();
  }
  if (threadIdx.x == 0) bsum[blockIdx.x] = sd[0];
}
__global__ void k_scan2(int* __restrict__ bsum, int nb){
  __shared__ int sd[256];
  int t = threadIdx.x;
  int v = (t < nb) ? bsum[t] : 0;
  sd[t] = v;
  __syncthreads();
  for (int off = 1; off < 256; off <<= 1){
    int u = (t >= off) ? sd[t-off] : 0;
    __syncthreads();
    sd[t] += u;
    __syncthreads();
  }
  if (t < nb) bsum[t] = sd[t] - v;
}
__global__ void k_scan3(const int* __restrict__ deg, const int* __restrict__ boff,
                        int* __restrict__ rowptr, int* __restrict__ cursor, int n){
  __shared__ int sd[256];
  int t = threadIdx.x;
  int i = blockIdx.x*256 + t;
  int v = (i < n) ? deg[i] : 0;
  sd[t] = v;
  __syncthreads();
  for (int off = 1; off < 256; off <<= 1){
    int u = (t >= off) ? sd[t-off] : 0;
    __syncthreads();
    sd[t] += u;
    __syncthreads();
  }
  int excl = sd[t] - v + boff[blockIdx.x];
  if (i < n){
    rowptr[i] = excl; cursor[i] = excl;
    if (i == n-1) rowptr[n] = excl + v;
  }
}
// fill: ONE 8B scatter per edge: sea[pos] = {src, ea-bits}
__global__ void k_fill_dst(const int* __restrict__ src, const int* __restrict__ dst,
                           const float* __restrict__ ea, int* __restrict__ cursor,
                           int2* __restrict__ sea, int ne){
  int e = blockIdx.x*blockDim.x + threadIdx.x;
  if (e >= ne) return;
  int pos = atomicAdd(&cursor[dst[e]], 1);
  sea[pos] = make_int2(src[e], __float_as_int(ea[e]));
}

// GATEConv edge logits over dst-sorted positions; 8 lanes/edge.
__global__ __launch_bounds__(256)
void k_edge_logit_gate(const unsigned short* __restrict__ xW1, const float* __restrict__ w1col,
                       const float* __restrict__ attl, const int2* __restrict__ sea,
                       float* __restrict__ logit_s, int ne){
  int tid = threadIdx.x;
  int j = blockIdx.x*32 + (tid >> 3);
  int g = tid & 7;
  if (j >= ne) return;
  int2 se = sea[j];
  int s = se.x;
  float eav = __int_as_float(se.y);
  const unsigned short* xr = &xW1[(size_t)s*H + g*16];
  short8 r0 = *(const short8*)xr;
  short8 r1 = *(const short8*)(xr + 8);
  float acc = 0.f;
  #pragma unroll
  for (int kk = 0; kk < 8; ++kk)
    acc += lrelu(bf2f((unsigned short)r0[kk]) + eav*w1col[g*16 + kk]) * attl[g*16 + kk];
  #pragma unroll
  for (int kk = 0; kk < 8; ++kk)
    acc += lrelu(bf2f((unsigned short)r1[kk]) + eav*w1col[g*16 + 8 + kk]) * attl[g*16 + 8 + kk];
  #pragma unroll
  for (int off = 1; off < 8; off <<= 1) acc += __shfl_xor(acc, off, 64);
  if (g == 0) logit_s[j] = acc;
}

// ---------------- per-node softmax + aggregation ----------------
__global__ void k_node_agg(const int* __restrict__ rowptr, const int2* __restrict__ sea,
                           const float* __restrict__ logit_s, const float* __restrict__ rdot,
                           const unsigned short* __restrict__ val, const float* __restrict__ bias,
                           unsigned short* __restrict__ hbuf, int n){
  int i = blockIdx.x*4 + (threadIdx.x >> 6);
  int lane = threadIdx.x & 63;
  if (i >= n) return;
  int b = rowptr[i], e1 = rowptr[i+1];
  float rd = rdot[i];
  float m = -1e30f;
  for (int j = b+lane; j < e1; j += 64) m = fmaxf(m, lrelu(logit_s[j] + rd));
  m = wredmax(m);
  float s = 0.f, ax = 0.f, ay = 0.f;
  for (int c0 = b; c0 < e1; c0 += 64){
    int cnt = min(64, e1 - c0);
    float wv = 0.f; int snv = 0;
    if (lane < cnt){
      snv = sea[c0 + lane].x;
      wv = expf(lrelu(logit_s[c0 + lane] + rd) - m);
    }
    s += wred(wv);
    int j = 0;
    for (; j+8 <= cnt; j += 8){
      #pragma unroll
      for (int u = 0; u < 8; ++u){
        float wq = rdlane(wv, j+u);
        int sq = rdlanei(snv, j+u);
        ushort2 v = *(const ushort2*)&val[(size_t)sq*H + 2*lane];
        ax += bf2f(v.x)*wq; ay += bf2f(v.y)*wq;
      }
    }
    for (; j < cnt; ++j){
      float wq = rdlane(wv, j);
      int sq = rdlanei(snv, j);
      ushort2 v = *(const ushort2*)&val[(size_t)sq*H + 2*lane];
      ax += bf2f(v.x)*wq; ay += bf2f(v.y)*wq;
    }
  }
  float inv = (s > 0.f) ? 1.f/s : 0.f;
  ushort2 o;
  o.x = f2bf(eluf(bias[2*lane]   + ax*inv));
  o.y = f2bf(eluf(bias[2*lane+1] + ay*inv));
  *(ushort2*)&hbuf[(size_t)i*H + 2*lane] = o;
}

// GAT variant: logit = lrelu(ssrc[src]+sdst[i]) inline
__global__ void k_node_agg_gat(const int* __restrict__ rowptr, const int2* __restrict__ sea,
                               const float* __restrict__ ssrc, const float* __restrict__ sdst,
                               const unsigned short* __restrict__ val, const float* __restrict__ bias,
                               unsigned short* __restrict__ hbuf, int n){
  int i = blockIdx.x*4 + (threadIdx.x >> 6);
  int lane = threadIdx.x & 63;
  if (i >= n) return;
  int b = rowptr[i], e1 = rowptr[i+1];
  float sdi = sdst[i];
  float m = -1e30f;
  for (int j = b+lane; j < e1; j += 64) m = fmaxf(m, lrelu(ssrc[sea[j].x] + sdi));
  m = wredmax(m);
  float s = 0.f, ax = 0.f, ay = 0.f;
  for (int c0 = b; c0 < e1; c0 += 64){
    int cnt = min(64, e1 - c0);
    float wv = 0.f; int snv = 0;
    if (lane < cnt){
      snv = sea[c0 + lane].x;
      wv = expf(lrelu(ssrc[snv] + sdi) - m);
    }
    s += wred(wv);
    int j = 0;
    for (; j+8 <= cnt; j += 8){
      #pragma unroll
      for (int u = 0; u < 8; ++u){
        float wq = rdlane(wv, j+u);
        int sq = rdlanei(snv, j+u);
        ushort2 v = *(const ushort2*)&val[(size_t)sq*H + 2*lane];
        ax += bf2f(v.x)*wq; ay += bf2f(v.y)*wq;
      }
    }
    for (; j < cnt; ++j){
      float wq = rdlane(wv, j);
      int sq = rdlanei(snv, j);
      ushort2 v = *(const ushort2*)&val[(size_t)sq*H + 2*lane];
      ax += bf2f(v.x)*wq; ay += bf2f(v.y)*wq;
    }
  }
  float inv = (s > 0.f) ? 1.f/s : 0.f;
  ushort2 o;
  o.x = f2bf(eluf(bias[2*lane]   + ax*inv));
  o.y = f2bf(eluf(bias[2*lane+1] + ay*inv));
  *(ushort2*)&hbuf[(size_t)i*H + 2*lane] = o;
}

// ---------------- molecule readout ----------------
__global__ void k_colsum(const unsigned short* __restrict__ x, float* __restrict__ outraw,
                         int n, int chunk){
  int t = threadIdx.x; // 64
  int start = blockIdx.x*chunk;
  int end = min(start + chunk, n);
  float s0 = 0.f, s1 = 0.f;
  for (int i = start; i < end; ++i){
    ushort2 v = *(const ushort2*)&x[(size_t)i*H + 2*t];
    s0 += bf2f(v.x); s1 += bf2f(v.y);
  }
  if (start < end){ atomicAdd(&outraw[2*t], s0); atomicAdd(&outraw[2*t+1], s1); }
}
__global__ void k_mol_prep(const float* __restrict__ outraw, const float* __restrict__ molW,
                           const float* __restrict__ attdst, float* __restrict__ hidvec,
                           float* __restrict__ cdst){
  __shared__ float hs[128];
  __shared__ float red[128];
  int t = threadIdx.x;
  float hv = fmaxf(outraw[t], 0.f);
  hs[t] = hv; hidvec[t] = hv;
  __syncthreads();
  float o = 0.f;
  for (int k = 0; k < 128; ++k) o += hs[k]*molW[t*128+k];
  red[t] = o * attdst[t];
  __syncthreads();
  for (int s = 64; s > 0; s >>= 1){
    if (t < s) red[t] += red[t+s];
    __syncthreads();
  }
  if (t == 0) cdst[0] = red[0];
}
// wave-reduced max: ONE atomicMax per wave
__global__ void k_mol_logit(float* __restrict__ a, const float* __restrict__ cdst,
                            unsigned* __restrict__ gmax, int n){
  int i = blockIdx.x*blockDim.x + threadIdx.x;
  int lane = threadIdx.x & 63;
  float l = -1e30f;
  if (i < n){
    l = lrelu(a[i] + cdst[0]);
    a[i] = l;
  }
  float mm = wredmax(l);
  if (lane == 0) atomicMax(gmax, fenc(mm));
}
__global__ void k_mol_exp(float* __restrict__ a, const unsigned* __restrict__ gmax,
                          float* __restrict__ gsum, int n){
  int i = blockIdx.x*blockDim.x + threadIdx.x;
  int lane = threadIdx.x & 63;
  float gm = fdec(gmax[0]);
  float ex = 0.f;
  if (i < n){ ex = expf(a[i] - gm); a[i] = ex; }
  float s = wred(ex);
  if (lane == 0) atomicAdd(gsum, s);
}
__global__ void k_mol_acc(const unsigned short* __restrict__ xs, const float* __restrict__ a,
                          float* __restrict__ num, int n, int chunk){
  int t = threadIdx.x; // 64
  int start = blockIdx.x*chunk;
  int end = min(start + chunk, n);
  float s0 = 0.f, s1 = 0.f;
  for (int i = start; i < end; ++i){
    float ai = a[i];
    ushort2 v = *(const ushort2*)&xs[(size_t)i*H + 2*t];
    s0 += bf2f(v.x)*ai; s1 += bf2f(v.y)*ai;
  }
  if (start < end){ atomicAdd(&num[2*t], s0); atomicAdd(&num[2*t+1], s1); }
}
__global__ void k_mol_final(const float* __restrict__ num, const float* __restrict__ gsum,
                            const float* __restrict__ molb, const float* __restrict__ hidvec,
                            const float* __restrict__ Wih, const float* __restrict__ Whh,
                            const float* __restrict__ bih, const float* __restrict__ bhh,
                            float* __restrict__ out){
  __shared__ float hv[128], hd[128];
  int t = threadIdx.x;
  hv[t] = eluf(num[t]/gsum[0] + molb[t]);
  hd[t] = hidvec[t];
  __syncthreads();
  float gr = bih[t], gz = bih[t+128], gn = bih[t+256];
  float hr = bhh[t], hz = bhh[t+128], hn = bhh[t+256];
  for (int k = 0; k < 128; ++k){
    float h = hv[k], d = hd[k];
    gr += h*Wih[t*128+k];       gz += h*Wih[(t+128)*128+k]; gn += h*Wih[(t+256)*128+k];
    hr += d*Whh[t*128+k];       hz += d*Whh[(t+128)*128+k]; hn += d*Whh[(t+256)*128+k];
  }
  float r = sigm(gr+hr), z = sigm(gz+hz);
  float nn = tanhf(gn + r*hn);
  float o = (1.f-z)*nn + z*hd[t];
  out[t] = fmaxf(o, 0.f);
}

extern "C" void kernel_launch(void* const* d_in, const int* in_sizes, int n_in,
                              void* d_out, int out_size, void* d_ws, size_t ws_size,
                              hipStream_t stream){
  const float* node_attr = (const float*)d_in[0];
  const int*   eidx      = (const int*)d_in[1];
  const float* eattr     = (const float*)d_in[2];
  const float* W_lin1    = (const float*)d_in[3];
  const float* b_lin1    = (const float*)d_in[4];
  const float* gate_W1   = (const float*)d_in[5];
  const float* gate_W2   = (const float*)d_in[6];
  const float* gate_att_l= (const float*)d_in[7];
  const float* gate_att_r= (const float*)d_in[8];
  const float* gate_b    = (const float*)d_in[9];
  const float* g1_Wih    = (const float*)d_in[10];
  const float* g1_Whh    = (const float*)d_in[11];
  const float* g1_bih    = (const float*)d_in[12];
  const float* g1_bhh    = (const float*)d_in[13];
  const float* atom_W    = (const float*)d_in[14];
  const float* atom_as   = (const float*)d_in[15];
  const float* atom_ad   = (const float*)d_in[16];
  const float* atom_b    = (const float*)d_in[17];
  const float* g2_Wih    = (const float*)d_in[18];
  const float* g2_Whh    = (const float*)d_in[19];
  const float* g2_bih    = (const float*)d_in[20];
  const float* g2_bhh    = (const float*)d_in[21];
  const float* mol_W     = (const float*)d_in[22];
  const float* mol_as    = (const float*)d_in[23];
  const float* mol_ad    = (const float*)d_in[24];
  const float* mol_b     = (const float*)d_in[25];
  const float* gm_Wih    = (const float*)d_in[26];
  const float* gm_Whh    = (const float*)d_in[27];
  const float* gm_bih    = (const float*)d_in[28];
  const float* gm_bhh    = (const float*)d_in[29];

  const int n  = in_sizes[0];
  const int ne = in_sizes[1] / 2;
  const int* src = eidx;
  const int* dst = eidx + ne;

  // ---- workspace layout ----
  const size_t NH = (size_t)n * H;
  unsigned short* us = (unsigned short*)d_ws;
  unsigned short* x_bf = us;            // [N,H]
  unsigned short* t0   = us + NH;       // [N,H]
  unsigned short* t1   = us + 2*NH;     // [N,H]
  unsigned short* hb   = us + 3*NH;     // [N,H]
  unsigned short* gi   = us + 4*NH;     // [N,384]
  unsigned short* gh   = us + 7*NH;     // [N,384]
  float* fb = (float*)(us + 10*NH);
  float* rdot = fb;                     // [N]
  float* ssrc = rdot + n;               // [N]
  float* sdst = ssrc + n;               // [N]
  float* logit_s = sdst + n;            // [E]
  int* deg    = (int*)(logit_s + ne);   // [N]
  int* cursor = deg + n;                // [N]
  int* rowptr = cursor + n;             // [N+1]
  int* bsum   = rowptr + n + 1;         // [256]
  size_t ioff = (size_t)(bsum + 256 - (int*)d_ws);
  ioff = (ioff + 1) & ~(size_t)1;       // 8B align for int2
  int2* sea  = (int2*)((int*)d_ws + ioff);   // [E]
  float* outraw = (float*)(sea + ne);   // [128]
  float* hidvec = outraw + 128;         // [128]
  float* cdstp  = hidvec + 128;         // [1]
  unsigned* gmax = (unsigned*)(cdstp + 1);
  float* gsum   = (float*)gmax + 1;
  float* numv   = gsum + 1;             // [128]
  float* w1col  = numv + 128 + 1;       // [128]
  unsigned short* wp = (unsigned short*)(w1col + 128);
  unsigned short* gW1bf  = wp;                 // 128*128 (gW2bf contiguous after)
  unsigned short* gW2bf  = gW1bf  + 128*H;
  unsigned short* atomWbf= gW2bf  + 128*H;
  unsigned short* molWbf = atomWbf+ 128*H;
  unsigned short* g1ihbf = molWbf + 128*H;     // 384*128 (hh contiguous after ih)
  unsigned short* g1hhbf = g1ihbf + 384*H;
  unsigned short* g2ihbf = g1hhbf + 384*H;
  unsigned short* g2hhbf = g2ihbf + 384*H;

  const int nb256      = (n + 255)/256;
  const int nwave4     = (n + 3)/4;
  const int e32_blocks = (ne + 31)/32;
  const int ethr       = (ne + 255)/256;
  const int nthr       = (n + 255)/256;
  const int nb         = (n + 255)/256;
  const int chunk      = (n + 255)/256;
  const int gru_blocks = (n*64 + 255)/256;

  // ---- weight casts (+deg zero, w1col pack, mol-scalar zero) + node init + CSR ----
  k_castall<<<1024,256,0,stream>>>(gate_W1, gate_W2, atom_W, mol_W,
                                   g1_Wih, g1_Whh, g2_Wih, g2_Whh, wp,
                                   deg, n, w1col, outraw, gmax, gsum, numv);
  k_node_init_rd<<<nwave4,256,0,stream>>>(node_attr, W_lin1, b_lin1, gate_att_r, x_bf, rdot, n);
  k_hist<<<ethr,256,0,stream>>>(dst, deg, ne);
  k_scan1<<<nb,256,0,stream>>>(deg, bsum, n);
  k_scan2<<<1,256,0,stream>>>(bsum, nb);
  k_scan3<<<nb,256,0,stream>>>(deg, bsum, rowptr, cursor, n);
  k_fill_dst<<<ethr,256,0,stream>>>(src, dst, eattr, cursor, sea, ne);

  // ---- GATEConv ----
  k_gemm_mfma<<<dim3(nb256,2),256,0,stream>>>(x_bf, gW1bf, t0, n, H, NH,
                                              nullptr, nullptr, nullptr, nullptr);
  k_edge_logit_gate<<<e32_blocks,256,0,stream>>>(t0, w1col, gate_att_l, sea, logit_s, ne);
  k_node_agg<<<nwave4,256,0,stream>>>(rowptr, sea, logit_s, rdot, t1, gate_b, hb, n);
  k_gemm_gru<<<dim3(nb256,6),256,0,stream>>>(hb, x_bf, g1ihbf, gi, gh, n);
  k_gru_combine<<<gru_blocks,256,0,stream>>>(gi, gh, g1_bih, g1_bhh, x_bf, n);

  // ---- GATConv ----
  k_gemm_mfma<<<dim3(nb256,1),256,0,stream>>>(x_bf, atomWbf, t0, n, H, 0,
                                              atom_as, atom_ad, ssrc, sdst);  // xt + dots
  k_node_agg_gat<<<nwave4,256,0,stream>>>(rowptr, sea, ssrc, sdst, t0, atom_b, hb, n);
  k_gemm_gru<<<dim3(nb256,6),256,0,stream>>>(hb, x_bf, g2ihbf, gi, gh, n);
  k_gru_combine<<<gru_blocks,256,0,stream>>>(gi, gh, g2_bih, g2_bhh, x_bf, n);

  // ---- molecule readout ----
  k_colsum<<<256,64,0,stream>>>(x_bf, outraw, n, chunk);
  k_mol_prep<<<1,128,0,stream>>>(outraw, mol_W, mol_ad, hidvec, cdstp);
  k_gemm_mfma<<<dim3(nb256,1),256,0,stream>>>(x_bf, molWbf, t1, n, H, 0,
                                              mol_as, nullptr, rdot, nullptr);  // xs + dot
  k_mol_logit<<<nthr,256,0,stream>>>(rdot, cdstp, gmax, n);
  k_mol_exp<<<nthr,256,0,stream>>>(rdot, gmax, gsum, n);
  k_mol_acc<<<256,64,0,stream>>>(t1, rdot, numv, n, chunk);
  k_mol_final<<<1,128,0,stream>>>(numv, gsum, mol_b, hidvec,
                                  gm_Wih, gm_Whh, gm_bih, gm_bhh, (float*)d_out);
}